// Round 1
// baseline (18608.128 us; speedup 1.0000x reference)
//
#include <hip/hip_runtime.h>
#include <hip/hip_bf16.h>
#include <cmath>

#define NVP 250
#define NN  16000
#define EN  95232
#define LRc 0.01f
#define SQ2 1.41421356237309515f

struct GP {
  const float* W; const float* bias; float gain;
  int M, K, m0, mA0, mo0;
  const float* zn; const float* la; const float* x1; const float* ef0;
  const float* agg; const float* cnt; const float* Ain;
  const int* src; const int* dst;
  float* outp; float* atomp;
};

template<int AMODE>
__device__ __forceinline__ float fetchA(int m, int k, const GP& p) {
  if (AMODE == 0) { // dense [M,512]
    return p.Ain[(size_t)(m - p.mA0) * p.K + k];
  } else if (AMODE == 1) { // P0 edge L1: [x0[src](515), x0[dst](515), ea(4)]
    int s = p.src[m], d = p.dst[m];
    if (k < 515)  { int j = k;       return (j < 512) ? p.zn[(s & 63)*512 + j] : p.la[s*3 + (j-512)]; }
    if (k < 1030) { int j = k - 515; return (j < 512) ? p.zn[(d & 63)*512 + j] : p.la[d*3 + (j-512)]; }
    int c = k - 1030;
    float r0 = p.la[d*3+0] - p.la[s*3+0];
    float r1 = p.la[d*3+1] - p.la[s*3+1];
    float r2 = p.la[d*3+2] - p.la[s*3+2];
    if (c == 0) return r0;
    if (c == 1) return r1;
    if (c == 2) return r2;
    return sqrtf(r0*r0 + r1*r1 + r2*r2);
  } else if (AMODE == 2) { // P0 node L1: [zn(512), la(3), la*cnt>0(3), aggef0(512)]
    if (k < 512) return p.zn[(m & 63)*512 + k];
    if (k < 515) return p.la[m*3 + (k-512)];
    if (k < 518) return (p.cnt[m] > 0.f) ? p.la[m*3 + (k-515)] : 0.f;
    return p.agg[(size_t)m*512 + (k-518)];
  } else if (AMODE == 3) { // P1 edge L1: [x1[src], x1[dst], ef0]
    int s = p.src[m], d = p.dst[m];
    if (k < 512)  return p.x1[(size_t)s*512 + k];
    if (k < 1024) return p.x1[(size_t)d*512 + (k-512)];
    return p.ef0[(size_t)m*512 + (k-1024)];
  } else { // 4: P1 node L1 on ws rows: [x1[n], agg1[n]], n = m*250
    int n = m * NVP;
    if (k < 512) return p.x1[(size_t)n*512 + k];
    return p.agg[(size_t)n*512 + (k-512)];
  }
}

// out[m][n] = leaky(gain * sum_k A(m,k) W[n][k] + 0.01*bias[n], 0.2) * sqrt2
// EPI 0: store outp[(m0+r-mo0)*512+n]; EPI 1: store ef0 + atomicAdd agg[dst];
// EPI 2: atomicAdd agg[dst] only.
template<int AMODE, int EPI>
__global__ __launch_bounds__(256) void gemm_k(GP p) {
  __shared__ float As[32][65];
  __shared__ float Bs[32][65];
  const int t  = threadIdx.x;
  const int ty = t >> 4, tx = t & 15;
  const int mBase = blockIdx.x * 64;
  const int nBase = blockIdx.y * 64;

  float acc[4][4] = {};
  for (int k0 = 0; k0 < p.K; k0 += 32) {
#pragma unroll
    for (int i = 0; i < 8; i++) {
      int idx = t + i*256;
      int mr = idx >> 5, kk = idx & 31;
      int r = mBase + mr, k = k0 + kk;
      float v = 0.f;
      if (r < p.M && k < p.K) v = fetchA<AMODE>(p.m0 + r, k, p);
      As[kk][mr] = v;
    }
#pragma unroll
    for (int i = 0; i < 8; i++) {
      int idx = t + i*256;
      int nr = idx >> 5, kk = idx & 31;
      int n = nBase + nr, k = k0 + kk;
      float v = 0.f;
      if (k < p.K) v = p.W[(size_t)n * p.K + k];
      Bs[kk][nr] = v;
    }
    __syncthreads();
#pragma unroll
    for (int kk = 0; kk < 32; kk++) {
      float a[4], b[4];
#pragma unroll
      for (int i = 0; i < 4; i++) a[i] = As[kk][ty*4+i];
#pragma unroll
      for (int j = 0; j < 4; j++) b[j] = Bs[kk][tx*4+j];
#pragma unroll
      for (int i = 0; i < 4; i++)
#pragma unroll
        for (int j = 0; j < 4; j++) acc[i][j] += a[i]*b[j];
    }
    __syncthreads();
  }

#pragma unroll
  for (int i = 0; i < 4; i++) {
    int r = mBase + ty*4 + i;
    if (r >= p.M) continue;
#pragma unroll
    for (int j = 0; j < 4; j++) {
      int n = nBase + tx*4 + j;
      float y = acc[i][j] * p.gain + p.bias[n] * LRc;
      y = (y > 0.f ? y : 0.2f*y) * SQ2;
      if (EPI == 0) {
        p.outp[(size_t)(p.m0 + r - p.mo0)*512 + n] = y;
      } else if (EPI == 1) {
        int g = p.m0 + r;
        p.outp[(size_t)g*512 + n] = y;
        atomicAdd(&p.atomp[(size_t)p.dst[g]*512 + n], y);
      } else {
        int g = p.m0 + r;
        atomicAdd(&p.atomp[(size_t)p.dst[g]*512 + n], y);
      }
    }
  }
}

__global__ __launch_bounds__(256) void rms_k(const float* z, float* zn) {
  int b = blockIdx.x, t = threadIdx.x;
  float s = 0.f;
  for (int j = t; j < 512; j += 256) { float v = z[b*512+j]; s += v*v; }
  for (int o = 32; o > 0; o >>= 1) s += __shfl_down(s, o);
  __shared__ float red[5];
  if ((t & 63) == 0) red[t >> 6] = s;
  __syncthreads();
  if (t == 0) {
    float tot = red[0]+red[1]+red[2]+red[3];
    red[4] = 1.0f / sqrtf(tot * (1.0f/512.0f) + 1e-8f);
  }
  __syncthreads();
  float r = red[4];
  for (int j = t; j < 512; j += 256) zn[b*512+j] = z[b*512+j] * r;
}

__global__ __launch_bounds__(256) void count_k(const int* dst, float* cnt, int E) {
  int e = blockIdx.x*256 + threadIdx.x;
  if (e < E) atomicAdd(&cnt[dst[e]], 1.0f);
}

__global__ __launch_bounds__(256) void cinv_k(const float* cnt, float* cinv, int n) {
  int i = blockIdx.x*256 + threadIdx.x;
  if (i < n) cinv[i] = 1.0f / fmaxf(cnt[i], 1.0f);
}

__global__ __launch_bounds__(256) void scale_k(float* a, const float* cinv, int total) {
  int i = blockIdx.x*256 + threadIdx.x;
  if (i < total) a[i] *= cinv[i >> 9];
}

__global__ __launch_bounds__(256) void expand_k(const float* x2, float* out, int total) {
  int i = blockIdx.x*256 + threadIdx.x;
  if (i < total) {
    int d = i & 511;
    int b = i / (14*512);
    out[i] = x2[b*512 + d];
  }
}

extern "C" void kernel_launch(void* const* d_in, const int* in_sizes, int n_in,
                              void* d_out, int out_size, void* d_ws, size_t ws_size,
                              hipStream_t stream) {
  const float* z     = (const float*)d_in[0];
  const float* la    = (const float*)d_in[1];
  const int*   ei    = (const int*)  d_in[2];
  const float* p0ew0 = (const float*)d_in[3];
  const float* p0eb0 = (const float*)d_in[4];
  const float* p0ew1 = (const float*)d_in[5];
  const float* p0eb1 = (const float*)d_in[6];
  const float* p0nw0 = (const float*)d_in[7];
  const float* p0nb0 = (const float*)d_in[8];
  const float* p0nw1 = (const float*)d_in[9];
  const float* p0nb1 = (const float*)d_in[10];
  const float* p1ew0 = (const float*)d_in[11];
  const float* p1eb0 = (const float*)d_in[12];
  const float* p1ew1 = (const float*)d_in[13];
  const float* p1eb1 = (const float*)d_in[14];
  const float* p1nw0 = (const float*)d_in[15];
  const float* p1nb0 = (const float*)d_in[16];
  const float* p1nw1 = (const float*)d_in[17];
  const float* p1nb1 = (const float*)d_in[18];
  const int* src = ei;
  const int* dst = ei + EN;

  char* ws = (char*)d_ws;
  size_t off = 0;
  auto al = [&](size_t bytes) -> float* {
    float* r = (float*)(ws + off);
    off += (bytes + 255) & ~(size_t)255;
    return r;
  };
  float* zn   = al(64*512*4);
  float* cnt  = al(NN*4);
  float* cinv = al(NN*4);
  float* big1 = al((size_t)NN*512*4);   // aggef0, later x1
  float* big2 = al((size_t)NN*512*4);   // node h, later agg1
  float* hn1  = al(64*512*4);
  float* x2   = al(64*512*4);
  float* ef0  = al((size_t)EN*512*4);
  size_t rem = (ws_size > off) ? (ws_size - off) : 0;
  long long chl = (long long)(rem / (512*4));
  int CH = (int)(chl > 16384 ? 16384 : chl);
  if (CH < 256) CH = 256;
  float* hbuf = (float*)(ws + off);

  hipMemsetAsync(cnt, 0, NN*4, stream);
  hipMemsetAsync(big1, 0, (size_t)NN*512*4, stream);
  rms_k<<<64, 256, 0, stream>>>(z, zn);
  count_k<<<(EN+255)/256, 256, 0, stream>>>(dst, cnt, EN);
  cinv_k<<<(NN+255)/256, 256, 0, stream>>>(cnt, cinv, NN);

  // ---- Processor 0, edge MLP (chunked) ----
  for (int m0 = 0; m0 < EN; m0 += CH) {
    int M = EN - m0 < CH ? EN - m0 : CH;
    GP p{};
    p.W = p0ew0; p.bias = p0eb0; p.gain = LRc / sqrtf(1034.f);
    p.M = M; p.K = 1034; p.m0 = m0; p.mA0 = 0; p.mo0 = m0;
    p.zn = zn; p.la = la; p.src = src; p.dst = dst; p.outp = hbuf;
    gemm_k<1,0><<<dim3((M+63)/64, 8), 256, 0, stream>>>(p);

    GP q{};
    q.W = p0ew1; q.bias = p0eb1; q.gain = LRc / sqrtf(512.f);
    q.M = M; q.K = 512; q.m0 = m0; q.mA0 = m0; q.mo0 = 0;
    q.Ain = hbuf; q.dst = dst; q.outp = ef0; q.atomp = big1;
    gemm_k<0,1><<<dim3((M+63)/64, 8), 256, 0, stream>>>(q);
  }
  scale_k<<<(NN*512+255)/256, 256, 0, stream>>>(big1, cinv, NN*512);

  // ---- Processor 0, node MLP ----
  {
    GP p{};
    p.W = p0nw0; p.bias = p0nb0; p.gain = LRc / sqrtf(1030.f);
    p.M = NN; p.K = 1030; p.m0 = 0; p.mo0 = 0;
    p.zn = zn; p.la = la; p.cnt = cnt; p.agg = big1; p.outp = big2;
    gemm_k<2,0><<<dim3(250, 8), 256, 0, stream>>>(p);

    GP q{};
    q.W = p0nw1; q.bias = p0nb1; q.gain = LRc / sqrtf(512.f);
    q.M = NN; q.K = 512; q.m0 = 0; q.mA0 = 0; q.mo0 = 0;
    q.Ain = big2; q.outp = big1;   // big1 becomes x1
    gemm_k<0,0><<<dim3(250, 8), 256, 0, stream>>>(q);
  }
  hipMemsetAsync(big2, 0, (size_t)NN*512*4, stream);  // big2 becomes agg1

  // ---- Processor 1, edge MLP (chunked; ef1 never stored) ----
  for (int m0 = 0; m0 < EN; m0 += CH) {
    int M = EN - m0 < CH ? EN - m0 : CH;
    GP p{};
    p.W = p1ew0; p.bias = p1eb0; p.gain = LRc / sqrtf(1536.f);
    p.M = M; p.K = 1536; p.m0 = m0; p.mo0 = m0;
    p.x1 = big1; p.ef0 = ef0; p.src = src; p.dst = dst; p.outp = hbuf;
    gemm_k<3,0><<<dim3((M+63)/64, 8), 256, 0, stream>>>(p);

    GP q{};
    q.W = p1ew1; q.bias = p1eb1; q.gain = LRc / sqrtf(512.f);
    q.M = M; q.K = 512; q.m0 = m0; q.mA0 = m0;
    q.Ain = hbuf; q.dst = dst; q.atomp = big2;
    gemm_k<0,2><<<dim3((M+63)/64, 8), 256, 0, stream>>>(q);
  }
  scale_k<<<(NN*512+255)/256, 256, 0, stream>>>(big2, cinv, NN*512);

  // ---- Processor 1, node MLP: only the 64 output rows ----
  {
    GP p{};
    p.W = p1nw0; p.bias = p1nb0; p.gain = LRc / sqrtf(1024.f);
    p.M = 64; p.K = 1024; p.m0 = 0; p.mo0 = 0;
    p.x1 = big1; p.agg = big2; p.outp = hn1;
    gemm_k<4,0><<<dim3(1, 8), 256, 0, stream>>>(p);

    GP q{};
    q.W = p1nw1; q.bias = p1nb1; q.gain = LRc / sqrtf(512.f);
    q.M = 64; q.K = 512; q.m0 = 0; q.mA0 = 0; q.mo0 = 0;
    q.Ain = hn1; q.outp = x2;
    gemm_k<0,0><<<dim3(1, 8), 256, 0, stream>>>(q);
  }
  expand_k<<<(64*14*512+255)/256, 256, 0, stream>>>(x2, (float*)d_out, 64*14*512);
}

// Round 3
// 1211.362 us; speedup vs baseline: 15.3613x; 15.3613x over previous
//
#include <hip/hip_runtime.h>
#include <hip/hip_bf16.h>
#include <cmath>

#define NVP 250
#define NN  16000
#define EN  95232
#define LRc 0.01f
#define SQ2 1.41421356237309515f

#define CAP_ES 1024
#define CAP_N1 2048
#define CAP_E0 8192
#define EBLK ((EN + 255) / 256)   // 372
#define NBLK ((NN + 255) / 256)   // 63

struct GP {
  const float* W; const float* bias; float gain;
  int M, K, Wld, Woff;
  const int* Mdev;
  const float* zn; const float* la; const float* x1; const float* ef0;
  const float* agg; const float* cnt; const float* Ain;
  const int* src; const int* dst; const int* rmap; const int* posOf;
  float* outp; float* atomp;
};

// AMODE 0: dense Ain[m*K+k]
// AMODE 2: P0 node L0, n=rmap[m]: [zn(n%64) 512 | la(n) 3 | cnt>0?la:0 3 | agg0(n)/cnt 512]
// AMODE 3: P1 edge L0, e=rmap[m]: [x1[src] 512 | x1[dst] 512 | ef0c[posOf[e]] 512]
// AMODE 4: P1 node L0, n=m*250:   [x1[n] 512 | agg1c[m]/cnt 512]
template<int AMODE>
__device__ __forceinline__ float fetchA(int m, int k, const GP& p) {
  if (AMODE == 0) {
    return p.Ain[(size_t)m * p.K + k];
  } else if (AMODE == 2) {
    int n = p.rmap[m];
    if (k < 512) return p.zn[(n & 63)*512 + k];
    if (k < 515) return p.la[n*3 + (k-512)];
    if (k < 518) return (p.cnt[n] > 0.f) ? p.la[n*3 + (k-515)] : 0.f;
    float rinv = 1.0f / fmaxf(p.cnt[n], 1.0f);
    return p.agg[(size_t)n*512 + (k-518)] * rinv;
  } else if (AMODE == 3) {
    int e = p.rmap[m];
    int s = p.src[e], d = p.dst[e];
    if (k < 512)  return p.x1[(size_t)s*512 + k];
    if (k < 1024) return p.x1[(size_t)d*512 + (k-512)];
    return p.ef0[(size_t)p.posOf[e]*512 + (k-1024)];
  } else { // 4
    int n = m * NVP;
    if (k < 512) return p.x1[(size_t)n*512 + k];
    float rinv = 1.0f / fmaxf(p.cnt[n], 1.0f);
    return p.agg[(size_t)m*512 + (k-512)] * rinv;
  }
}

// EPI 0: store outp[m]. EPI 1: store + atomicAdd agg0[dst[rmap[m]]].
// EPI 2: atomicAdd agg1c[dst[rmap[m]]/250]. EPI 5: store outp[rmap[m]].
// EPI 6: raw store (no activation/bias/gain) — for Ts/Td tables.
template<int AMODE, int EPI>
__global__ __launch_bounds__(256) void gemm_k(GP p) {
  int M = p.Mdev ? *p.Mdev : p.M;
  if (M > p.M) M = p.M;
  const int mBase = blockIdx.x * 64;
  if (mBase >= M) return;
  const int nBase = blockIdx.y * 64;
  __shared__ float As[32][65];
  __shared__ float Bs[32][65];
  const int t  = threadIdx.x;
  const int ty = t >> 4, tx = t & 15;

  float acc[4][4] = {};
  for (int k0 = 0; k0 < p.K; k0 += 32) {
#pragma unroll
    for (int i = 0; i < 8; i++) {
      int idx = t + i*256;
      int mr = idx >> 5, kk = idx & 31;
      int r = mBase + mr, k = k0 + kk;
      float v = 0.f;
      if (r < M && k < p.K) v = fetchA<AMODE>(r, k, p);
      As[kk][mr] = v;
    }
#pragma unroll
    for (int i = 0; i < 8; i++) {
      int idx = t + i*256;
      int nr = idx >> 5, kk = idx & 31;
      int n = nBase + nr, k = k0 + kk;
      float v = 0.f;
      if (k < p.K) v = p.W[(size_t)n * p.Wld + p.Woff + k];
      Bs[kk][nr] = v;
    }
    __syncthreads();
#pragma unroll
    for (int kk = 0; kk < 32; kk++) {
      float a[4], b[4];
#pragma unroll
      for (int i = 0; i < 4; i++) a[i] = As[kk][ty*4+i];
#pragma unroll
      for (int j = 0; j < 4; j++) b[j] = Bs[kk][tx*4+j];
#pragma unroll
      for (int i = 0; i < 4; i++)
#pragma unroll
        for (int j = 0; j < 4; j++) acc[i][j] += a[i]*b[j];
    }
    __syncthreads();
  }

#pragma unroll
  for (int i = 0; i < 4; i++) {
    int r = mBase + ty*4 + i;
    if (r >= M) continue;
#pragma unroll
    for (int j = 0; j < 4; j++) {
      int n = nBase + tx*4 + j;
      if (EPI == 6) {
        p.outp[(size_t)r*512 + n] = acc[i][j];
        continue;
      }
      float y = acc[i][j] * p.gain + p.bias[n] * LRc;
      y = (y > 0.f ? y : 0.2f*y) * SQ2;
      if (EPI == 0) {
        p.outp[(size_t)r*512 + n] = y;
      } else if (EPI == 1) {
        p.outp[(size_t)r*512 + n] = y;
        atomicAdd(&p.atomp[(size_t)p.dst[p.rmap[r]]*512 + n], y);
      } else if (EPI == 2) {
        atomicAdd(&p.atomp[(size_t)(p.dst[p.rmap[r]] / NVP)*512 + n], y);
      } else { // 5
        p.outp[(size_t)p.rmap[r]*512 + n] = y;
      }
    }
  }
}

__global__ __launch_bounds__(256) void rms_k(const float* z, float* zn) {
  int b = blockIdx.x, t = threadIdx.x;
  float s = 0.f;
  for (int j = t; j < 512; j += 256) { float v = z[b*512+j]; s += v*v; }
  for (int o = 32; o > 0; o >>= 1) s += __shfl_down(s, o);
  __shared__ float red[5];
  if ((t & 63) == 0) red[t >> 6] = s;
  __syncthreads();
  if (t == 0) {
    float tot = red[0]+red[1]+red[2]+red[3];
    red[4] = 1.0f / sqrtf(tot * (1.0f/512.0f) + 1e-8f);
  }
  __syncthreads();
  float r = red[4];
  for (int j = t; j < 512; j += 256) zn[b*512+j] = z[b*512+j] * r;
}

__global__ __launch_bounds__(256) void initneed_k(int* need) {
  int n = blockIdx.x*256 + threadIdx.x;
  if (n < NN) need[n] = ((n % NVP) == 0) ? 1 : 0;
}

__global__ __launch_bounds__(256) void count_k(const int* dst, float* cnt) {
  int e = blockIdx.x*256 + threadIdx.x;
  if (e < EN) atomicAdd(&cnt[dst[e]], 1.0f);  // integer-valued: exact
}

// ---- deterministic compaction: count / scan / emit ----
__device__ __forceinline__ int blockCount(int pred, int* ws4) {
  unsigned long long m = __ballot(pred);
  int lane = threadIdx.x & 63, w = threadIdx.x >> 6;
  if (lane == 0) ws4[w] = __popcll(m);
  __syncthreads();
  return ws4[0] + ws4[1] + ws4[2] + ws4[3];
}
__device__ __forceinline__ int blockRank(int pred, int* ws4) {
  unsigned long long m = __ballot(pred);
  int lane = threadIdx.x & 63, w = threadIdx.x >> 6;
  if (lane == 0) ws4[w] = __popcll(m);
  __syncthreads();
  int off = 0;
  for (int i = 0; i < w; i++) off += ws4[i];
  return off + __popcll(m & ((1ull << lane) - 1ull));
}

__global__ __launch_bounds__(256) void cntES_k(const int* dst, int* bcnt) {
  __shared__ int ws4[4];
  int e = blockIdx.x*256 + threadIdx.x;
  int pred = (e < EN) && (dst[e] % NVP == 0);
  int c = blockCount(pred, ws4);
  if (threadIdx.x == 0) bcnt[blockIdx.x] = c;
}
__global__ __launch_bounds__(256) void emitES_k(const int* src, const int* dst,
                                                const int* boff, int* listES, int* need) {
  __shared__ int ws4[4];
  int e = blockIdx.x*256 + threadIdx.x;
  int pred = (e < EN) && (dst[e] % NVP == 0);
  int rank = blockRank(pred, ws4);
  if (pred) {
    int pos = boff[blockIdx.x] + rank;
    if (pos < CAP_ES) listES[pos] = e;
    need[src[e]] = 1;
  }
}
__global__ __launch_bounds__(256) void cntE0_k(const int* dst, const int* need, int* bcnt) {
  __shared__ int ws4[4];
  int e = blockIdx.x*256 + threadIdx.x;
  int pred = (e < EN) && need[dst[e]];
  int c = blockCount(pred, ws4);
  if (threadIdx.x == 0) bcnt[blockIdx.x] = c;
}
__global__ __launch_bounds__(256) void emitE0_k(const int* dst, const int* need,
                                                const int* boff, int* listE0, int* posOf) {
  __shared__ int ws4[4];
  int e = blockIdx.x*256 + threadIdx.x;
  int pred = (e < EN) && need[dst[e]];
  int rank = blockRank(pred, ws4);
  if (pred) {
    int pos = boff[blockIdx.x] + rank;
    if (pos < CAP_E0) { listE0[pos] = e; posOf[e] = pos; }
  }
}
__global__ __launch_bounds__(256) void cntN1_k(const int* need, int* bcnt) {
  __shared__ int ws4[4];
  int n = blockIdx.x*256 + threadIdx.x;
  int pred = (n < NN) && need[n];
  int c = blockCount(pred, ws4);
  if (threadIdx.x == 0) bcnt[blockIdx.x] = c;
}
__global__ __launch_bounds__(256) void emitN1_k(const int* need, const int* boff, int* listN1) {
  __shared__ int ws4[4];
  int n = blockIdx.x*256 + threadIdx.x;
  int pred = (n < NN) && need[n];
  int rank = blockRank(pred, ws4);
  if (pred) {
    int pos = boff[blockIdx.x] + rank;
    if (pos < CAP_N1) listN1[pos] = n;
  }
}

// single-block exclusive scan of n<=512 block counts; tot <- total
__global__ __launch_bounds__(512) void scan_k(const int* bcnt, int n, int* boff, int* tot) {
  __shared__ int s[512];
  int t = threadIdx.x;
  int orig = (t < n) ? bcnt[t] : 0;
  s[t] = orig;
  __syncthreads();
  for (int o = 1; o < 512; o <<= 1) {
    int v = (t >= o) ? s[t-o] : 0;
    __syncthreads();
    s[t] += v;
    __syncthreads();
  }
  if (t < n) boff[t] = s[t] - orig;
  if (t == n-1) *tot = s[t];
}

// transpose the 10 "small" columns of W0
__global__ __launch_bounds__(256) void buildw0s_k(const float* W0, float* w0s) {
  int c = blockIdx.x*256 + threadIdx.x;
  if (c >= 512) return;
  const float* row = W0 + (size_t)c*1034;
  w0s[0*512+c] = row[512];  w0s[1*512+c] = row[513];  w0s[2*512+c] = row[514];
  w0s[3*512+c] = row[1027]; w0s[4*512+c] = row[1028]; w0s[5*512+c] = row[1029];
  w0s[6*512+c] = row[1030]; w0s[7*512+c] = row[1031]; w0s[8*512+c] = row[1032];
  w0s[9*512+c] = row[1033];
}

// P0 edge L0 via tables
__global__ __launch_bounds__(256) void edge0_k(const int* nE0p, const int* listE0,
                                               const int* src, const int* dst,
                                               const float* Ts, const float* Td,
                                               const float* la, const float* w0s,
                                               const float* b0, float* h0c) {
  int i = blockIdx.x;
  int n0 = *nE0p; if (n0 > CAP_E0) n0 = CAP_E0;
  if (i >= n0) return;
  int e = listE0[i];
  int s = src[e], d = dst[e];
  float a0 = la[s*3], a1 = la[s*3+1], a2 = la[s*3+2];
  float c0 = la[d*3], c1 = la[d*3+1], c2 = la[d*3+2];
  float r0 = c0-a0, r1 = c1-a1, r2 = c2-a2;
  float dn = sqrtf(r0*r0 + r1*r1 + r2*r2);
  const float g = LRc / 32.1558704423f; // sqrt(1034)
  const float* ts = Ts + (size_t)(s & 63)*512;
  const float* td = Td + (size_t)(d & 63)*512;
  for (int c = threadIdx.x; c < 512; c += 256) {
    float pre = ts[c] + td[c]
      + a0*w0s[0*512+c] + a1*w0s[1*512+c] + a2*w0s[2*512+c]
      + c0*w0s[3*512+c] + c1*w0s[4*512+c] + c2*w0s[5*512+c]
      + r0*w0s[6*512+c] + r1*w0s[7*512+c] + r2*w0s[8*512+c]
      + dn*w0s[9*512+c];
    float y = pre*g + b0[c]*LRc;
    y = (y > 0.f ? y : 0.2f*y) * SQ2;
    h0c[(size_t)i*512 + c] = y;
  }
}

__global__ __launch_bounds__(256) void expand_k(const float* x2, float* out, int total) {
  int i = blockIdx.x*256 + threadIdx.x;
  if (i < total) {
    int d = i & 511;
    int b = i / (14*512);
    out[i] = x2[b*512 + d];
  }
}

extern "C" void kernel_launch(void* const* d_in, const int* in_sizes, int n_in,
                              void* d_out, int out_size, void* d_ws, size_t ws_size,
                              hipStream_t stream) {
  const float* z     = (const float*)d_in[0];
  const float* la    = (const float*)d_in[1];
  const int*   ei    = (const int*)  d_in[2];
  const float* p0ew0 = (const float*)d_in[3];
  const float* p0eb0 = (const float*)d_in[4];
  const float* p0ew1 = (const float*)d_in[5];
  const float* p0eb1 = (const float*)d_in[6];
  const float* p0nw0 = (const float*)d_in[7];
  const float* p0nb0 = (const float*)d_in[8];
  const float* p0nw1 = (const float*)d_in[9];
  const float* p0nb1 = (const float*)d_in[10];
  const float* p1ew0 = (const float*)d_in[11];
  const float* p1eb0 = (const float*)d_in[12];
  const float* p1ew1 = (const float*)d_in[13];
  const float* p1eb1 = (const float*)d_in[14];
  const float* p1nw0 = (const float*)d_in[15];
  const float* p1nb0 = (const float*)d_in[16];
  const float* p1nw1 = (const float*)d_in[17];
  const float* p1nb1 = (const float*)d_in[18];
  const int* src = ei;
  const int* dst = ei + EN;

  char* ws = (char*)d_ws;
  size_t off = 0;
  auto al = [&](size_t bytes) -> void* {
    void* r = (void*)(ws + off);
    off += (bytes + 255) & ~(size_t)255;
    return r;
  };
  int*   tot    = (int*)  al(3*4);
  float* cnt    = (float*)al(NN*4);
  int*   need   = (int*)  al(NN*4);
  int*   posOf  = (int*)  al((size_t)EN*4);
  int*   bcntE  = (int*)  al(EBLK*4);
  int*   boffE  = (int*)  al(EBLK*4);
  int*   bcntN  = (int*)  al(NBLK*4);
  int*   boffN  = (int*)  al(NBLK*4);
  int*   listES = (int*)  al(CAP_ES*4);
  int*   listN1 = (int*)  al(CAP_N1*4);
  int*   listE0 = (int*)  al(CAP_E0*4);
  float* zn     = (float*)al(64*512*4);
  float* Ts     = (float*)al(64*512*4);
  float* Td     = (float*)al(64*512*4);
  float* w0s    = (float*)al(10*512*4);
  float* h0c    = (float*)al((size_t)CAP_E0*512*4);
  float* ef0c   = (float*)al((size_t)CAP_E0*512*4);
  float* agg0   = (float*)al((size_t)NN*512*4);
  float* x1     = (float*)al((size_t)NN*512*4);
  float* agg1c  = (float*)al(64*512*4);
  float* hn64   = (float*)al(64*512*4);
  float* x2     = (float*)al(64*512*4);

  // Zero the entire used region: every call starts from the identical context.
  hipMemsetAsync(ws, 0, off, stream);

  rms_k<<<64, 256, 0, stream>>>(z, zn);
  initneed_k<<<NBLK, 256, 0, stream>>>(need);
  count_k<<<EBLK, 256, 0, stream>>>(dst, cnt);

  cntES_k<<<EBLK, 256, 0, stream>>>(dst, bcntE);
  scan_k<<<1, 512, 0, stream>>>(bcntE, EBLK, boffE, tot+0);
  emitES_k<<<EBLK, 256, 0, stream>>>(src, dst, boffE, listES, need);

  cntE0_k<<<EBLK, 256, 0, stream>>>(dst, need, bcntE);
  scan_k<<<1, 512, 0, stream>>>(bcntE, EBLK, boffE, tot+1);
  emitE0_k<<<EBLK, 256, 0, stream>>>(dst, need, boffE, listE0, posOf);

  cntN1_k<<<NBLK, 256, 0, stream>>>(need, bcntN);
  scan_k<<<1, 512, 0, stream>>>(bcntN, NBLK, boffN, tot+2);
  emitN1_k<<<NBLK, 256, 0, stream>>>(need, boffN, listN1);

  buildw0s_k<<<2, 256, 0, stream>>>(p0ew0, w0s);
  // Ts = zn @ W0[:, 0:512]^T ; Td = zn @ W0[:, 515:1027]^T  (raw, no epilogue)
  {
    GP p{}; p.W = p0ew0; p.K = 512; p.Wld = 1034; p.Woff = 0;
    p.M = 64; p.Mdev = nullptr; p.Ain = zn; p.outp = Ts;
    gemm_k<0,6><<<dim3(1, 8), 256, 0, stream>>>(p);
    p.Woff = 515; p.outp = Td;
    gemm_k<0,6><<<dim3(1, 8), 256, 0, stream>>>(p);
  }

  edge0_k<<<CAP_E0, 256, 0, stream>>>(tot+1, listE0, src, dst, Ts, Td, la, w0s, p0eb0, h0c);

  // P0 edge L1 -> ef0c + atomic agg0
  {
    GP p{}; p.W = p0ew1; p.bias = p0eb1; p.gain = LRc/sqrtf(512.f);
    p.M = CAP_E0; p.K = 512; p.Wld = 512; p.Woff = 0; p.Mdev = tot+1;
    p.Ain = h0c; p.rmap = listE0; p.dst = dst; p.outp = ef0c; p.atomp = agg0;
    gemm_k<0,1><<<dim3(CAP_E0/64, 8), 256, 0, stream>>>(p);
  }
  // P0 node MLP on listN1 -> x1 (scatter)
  {
    GP p{}; p.W = p0nw0; p.bias = p0nb0; p.gain = LRc/sqrtf(1030.f);
    p.M = CAP_N1; p.K = 1030; p.Wld = 1030; p.Woff = 0; p.Mdev = tot+2;
    p.rmap = listN1; p.zn = zn; p.la = la; p.cnt = cnt; p.agg = agg0; p.outp = h0c;
    gemm_k<2,0><<<dim3(CAP_N1/64, 8), 256, 0, stream>>>(p);

    GP q{}; q.W = p0nw1; q.bias = p0nb1; q.gain = LRc/sqrtf(512.f);
    q.M = CAP_N1; q.K = 512; q.Wld = 512; q.Woff = 0; q.Mdev = tot+2;
    q.Ain = h0c; q.rmap = listN1; q.outp = x1;
    gemm_k<0,5><<<dim3(CAP_N1/64, 8), 256, 0, stream>>>(q);
  }
  // P1 edge MLP on listES -> atomic agg1c
  {
    GP p{}; p.W = p1ew0; p.bias = p1eb0; p.gain = LRc/sqrtf(1536.f);
    p.M = CAP_ES; p.K = 1536; p.Wld = 1536; p.Woff = 0; p.Mdev = tot+0;
    p.rmap = listES; p.src = src; p.dst = dst; p.x1 = x1; p.ef0 = ef0c; p.posOf = posOf;
    p.outp = h0c;
    gemm_k<3,0><<<dim3(CAP_ES/64, 8), 256, 0, stream>>>(p);

    GP q{}; q.W = p1ew1; q.bias = p1eb1; q.gain = LRc/sqrtf(512.f);
    q.M = CAP_ES; q.K = 512; q.Wld = 512; q.Woff = 0; q.Mdev = tot+0;
    q.Ain = h0c; q.rmap = listES; q.dst = dst; q.atomp = agg1c;
    gemm_k<0,2><<<dim3(CAP_ES/64, 8), 256, 0, stream>>>(q);
  }
  // P1 node MLP on the 64 output rows
  {
    GP p{}; p.W = p1nw0; p.bias = p1nb0; p.gain = LRc/sqrtf(1024.f);
    p.M = 64; p.K = 1024; p.Wld = 1024; p.Woff = 0; p.Mdev = nullptr;
    p.x1 = x1; p.agg = agg1c; p.cnt = cnt; p.outp = hn64;
    gemm_k<4,0><<<dim3(1, 8), 256, 0, stream>>>(p);

    GP q{}; q.W = p1nw1; q.bias = p1nb1; q.gain = LRc/sqrtf(512.f);
    q.M = 64; q.K = 512; q.Wld = 512; q.Woff = 0; q.Mdev = nullptr;
    q.Ain = hn64; q.outp = x2;
    gemm_k<0,0><<<dim3(1, 8), 256, 0, stream>>>(q);
  }
  expand_k<<<(64*14*512+255)/256, 256, 0, stream>>>(x2, (float*)d_out, 64*14*512);
}

// Round 4
// 410.255 us; speedup vs baseline: 45.3575x; 2.9527x over previous
//
#include <hip/hip_runtime.h>
#include <hip/hip_bf16.h>
#include <cmath>

#define NVP 250
#define NN  16000
#define EN  95232
#define LRc 0.01f
#define SQ2 1.41421356237309515f

#define CAP_ES 1024
#define CAP_N1 2048
#define CAP_E0 8192
#define EBLK ((EN + 255) / 256)   // 372
#define NBLK ((NN + 255) / 256)   // 63
#define SK_T 4                    // split-K for Ts/Td/T0 tables

struct GPP {
  const float* W; int Wld, Woff, K, KC, Mcap, Mfix;
  const int* Mdev;
  const float* Ain;                                   // AMODE 0 (stride == K)
  const float* la; const float* cnt; const float* agg;// AMODE 2,4
  const float* x1; const float* ef0;                  // AMODE 3,4
  const int* posOf; const int* posN;
  const int* src; const int* dst; const int* rmap;
  float* pbuf;
};

// AMODE 0: dense Ain[m*K+k]
// AMODE 2: P0 node L0 (K=518), n=rmap[m]: [la 3 | cnt>0?la:0 3 | agg0c[m]/cnt 512]
// AMODE 3: P1 edge L0 (K=1536), e=rmap[m]: [x1c[posN[src]] | x1c[posN[dst]] | ef0c[posOf[e]]]
// AMODE 4: P1 node L0 (K=1024), n=m*250: [x1c[posN[n]] | agg1c[m]/cnt[n]]
template<int AMODE>
__device__ __forceinline__ float fetchA(int m, int k, const GPP& p) {
  if (AMODE == 0) {
    return p.Ain[(size_t)m * p.K + k];
  } else if (AMODE == 2) {
    int n = p.rmap[m];
    if (k < 3) return p.la[n*3 + k];
    if (k < 6) return (p.cnt[n] > 0.f) ? p.la[n*3 + (k-3)] : 0.f;
    float rinv = 1.0f / fmaxf(p.cnt[n], 1.0f);
    return p.agg[(size_t)m*512 + (k-6)] * rinv;
  } else if (AMODE == 3) {
    int e = p.rmap[m];
    if (k < 512)  return p.x1[(size_t)p.posN[p.src[e]]*512 + k];
    if (k < 1024) return p.x1[(size_t)p.posN[p.dst[e]]*512 + (k-512)];
    return p.ef0[(size_t)p.posOf[e]*512 + (k-1024)];
  } else { // 4
    int n = m * NVP;
    if (k < 512) return p.x1[(size_t)p.posN[n]*512 + k];
    float rinv = 1.0f / fmaxf(p.cnt[n], 1.0f);
    return p.agg[(size_t)m*512 + (k-512)] * rinv;
  }
}

// Split-K partial GEMM: BM=32, BN=64, BK=32; grid (Mcap/32, 8, SK).
// pbuf[z][m][n] = sum over k in [z*KC, min(K,(z+1)*KC)) of A(m,k)*W[n][Woff+k]. Raw.
template<int AMODE>
__global__ __launch_bounds__(256) void gemmP(GPP p) {
  int M = p.Mdev ? *p.Mdev : p.Mfix;
  if (M > p.Mcap) M = p.Mcap;
  const int mBase = blockIdx.x * 32;
  if (mBase >= M) return;
  const int nBase = blockIdx.y * 64;
  const int z = blockIdx.z;
  const int kBeg = z * p.KC;
  int kEnd = kBeg + p.KC; if (kEnd > p.K) kEnd = p.K;

  __shared__ float As[32][33];   // [kk][mr]
  __shared__ float Bs[32][65];   // [kk][nr]
  const int t = threadIdx.x;
  const int tx = t & 15, ty = t >> 4;

  float acc[2][4] = {};
  for (int k0 = kBeg; k0 < kEnd; k0 += 32) {
#pragma unroll
    for (int i = 0; i < 4; i++) {
      int idx = t*4 + i;
      int mr = idx >> 5, kk = idx & 31;
      int r = mBase + mr, k = k0 + kk;
      float v = 0.f;
      if (r < M && k < kEnd) v = fetchA<AMODE>(r, k, p);
      As[kk][mr] = v;
    }
#pragma unroll
    for (int i = 0; i < 8; i++) {
      int idx = t*8 + i;
      int nr = idx >> 5, kk = idx & 31;
      int k = k0 + kk;
      float v = 0.f;
      if (k < kEnd) v = p.W[(size_t)(nBase + nr) * p.Wld + p.Woff + k];
      Bs[kk][nr] = v;
    }
    __syncthreads();
#pragma unroll
    for (int kk = 0; kk < 32; kk++) {
      float a[2], b[4];
#pragma unroll
      for (int i = 0; i < 2; i++) a[i] = As[kk][ty*2+i];
#pragma unroll
      for (int j = 0; j < 4; j++) b[j] = Bs[kk][tx*4+j];
#pragma unroll
      for (int i = 0; i < 2; i++)
#pragma unroll
        for (int j = 0; j < 4; j++) acc[i][j] += a[i]*b[j];
    }
    __syncthreads();
  }
#pragma unroll
  for (int i = 0; i < 2; i++) {
    int r = mBase + ty*2 + i;
#pragma unroll
    for (int j = 0; j < 4; j++) {
      p.pbuf[((size_t)z * p.Mcap + r)*512 + nBase + tx*4 + j] = acc[i][j];
    }
  }
}

struct EPP {
  const float* pbuf; int SK, Mcap, Mfix;
  const int* Mdev;
  const float* bias; float gain;
  const float* T0p;                 // EPI 7: add sum_z T0p[z][(rmap[m]&63)]
  const int* rmap; const int* dst; const int* posN;
  float* outp; float* atomp;
};

// EPI 0: store outp[m]. EPI 1: store outp[m] + atomicAdd agg0c[posN[dst[rmap[m]]]].
// EPI 2: atomicAdd agg1c[dst[rmap[m]]/250]. EPI 7: add T0 table, store outp[m].
template<int EPI>
__global__ __launch_bounds__(256) void epi_k(EPP e) {
  int M = e.Mdev ? *e.Mdev : e.Mfix;
  if (M > e.Mcap) M = e.Mcap;
  int i = blockIdx.x*256 + threadIdx.x;
  if (i >= M*512) return;
  int m = i >> 9, n = i & 511;
  float s = 0.f;
  for (int z = 0; z < e.SK; z++) s += e.pbuf[((size_t)z*e.Mcap + m)*512 + n];
  if (EPI == 7) {
    int r = e.rmap[m] & 63;
    for (int z = 0; z < SK_T; z++) s += e.T0p[((size_t)z*64 + r)*512 + n];
  }
  float y = s * e.gain + e.bias[n] * LRc;
  y = (y > 0.f ? y : 0.2f*y) * SQ2;
  if (EPI == 0 || EPI == 7) {
    e.outp[(size_t)m*512 + n] = y;
  } else if (EPI == 1) {
    e.outp[(size_t)m*512 + n] = y;
    atomicAdd(&e.atomp[(size_t)e.posN[e.dst[e.rmap[m]]]*512 + n], y);
  } else { // 2
    atomicAdd(&e.atomp[(size_t)(e.dst[e.rmap[m]] / NVP)*512 + n], y);
  }
}

__global__ __launch_bounds__(256) void rms_k(const float* z, float* zn) {
  int b = blockIdx.x, t = threadIdx.x;
  float s = 0.f;
  for (int j = t; j < 512; j += 256) { float v = z[b*512+j]; s += v*v; }
  for (int o = 32; o > 0; o >>= 1) s += __shfl_down(s, o);
  __shared__ float red[5];
  if ((t & 63) == 0) red[t >> 6] = s;
  __syncthreads();
  if (t == 0) {
    float tot = red[0]+red[1]+red[2]+red[3];
    red[4] = 1.0f / sqrtf(tot * (1.0f/512.0f) + 1e-8f);
  }
  __syncthreads();
  float r = red[4];
  for (int j = t; j < 512; j += 256) zn[b*512+j] = z[b*512+j] * r;
}

__global__ __launch_bounds__(256) void initneed_k(int* need) {
  int n = blockIdx.x*256 + threadIdx.x;
  if (n < NN) need[n] = ((n % NVP) == 0) ? 1 : 0;
}

__global__ __launch_bounds__(256) void count_k(const int* dst, float* cnt) {
  int e = blockIdx.x*256 + threadIdx.x;
  if (e < EN) atomicAdd(&cnt[dst[e]], 1.0f);  // integer-valued: exact & order-free
}

// ---- deterministic compaction ----
__device__ __forceinline__ int blockCount(int pred, int* ws4) {
  unsigned long long m = __ballot(pred);
  int lane = threadIdx.x & 63, w = threadIdx.x >> 6;
  if (lane == 0) ws4[w] = __popcll(m);
  __syncthreads();
  return ws4[0] + ws4[1] + ws4[2] + ws4[3];
}
__device__ __forceinline__ int blockRank(int pred, int* ws4) {
  unsigned long long m = __ballot(pred);
  int lane = threadIdx.x & 63, w = threadIdx.x >> 6;
  if (lane == 0) ws4[w] = __popcll(m);
  __syncthreads();
  int off = 0;
  for (int i = 0; i < w; i++) off += ws4[i];
  return off + __popcll(m & ((1ull << lane) - 1ull));
}

__global__ __launch_bounds__(256) void cntES_k(const int* dst, int* bcnt) {
  __shared__ int ws4[4];
  int e = blockIdx.x*256 + threadIdx.x;
  int pred = (e < EN) && (dst[e] % NVP == 0);
  int c = blockCount(pred, ws4);
  if (threadIdx.x == 0) bcnt[blockIdx.x] = c;
}
__global__ __launch_bounds__(256) void emitES_k(const int* src, const int* dst,
                                                const int* boff, int* listES, int* need) {
  __shared__ int ws4[4];
  int e = blockIdx.x*256 + threadIdx.x;
  int pred = (e < EN) && (dst[e] % NVP == 0);
  int rank = blockRank(pred, ws4);
  if (pred) {
    int pos = boff[blockIdx.x] + rank;
    if (pos < CAP_ES) listES[pos] = e;
    need[src[e]] = 1;
  }
}
__global__ __launch_bounds__(256) void cntE0_k(const int* dst, const int* need, int* bcnt) {
  __shared__ int ws4[4];
  int e = blockIdx.x*256 + threadIdx.x;
  int pred = (e < EN) && need[dst[e]];
  int c = blockCount(pred, ws4);
  if (threadIdx.x == 0) bcnt[blockIdx.x] = c;
}
__global__ __launch_bounds__(256) void emitE0_k(const int* dst, const int* need,
                                                const int* boff, int* listE0, int* posOf) {
  __shared__ int ws4[4];
  int e = blockIdx.x*256 + threadIdx.x;
  int pred = (e < EN) && need[dst[e]];
  int rank = blockRank(pred, ws4);
  if (pred) {
    int pos = boff[blockIdx.x] + rank;
    if (pos < CAP_E0) { listE0[pos] = e; posOf[e] = pos; }
  }
}
__global__ __launch_bounds__(256) void cntN1_k(const int* need, int* bcnt) {
  __shared__ int ws4[4];
  int n = blockIdx.x*256 + threadIdx.x;
  int pred = (n < NN) && need[n];
  int c = blockCount(pred, ws4);
  if (threadIdx.x == 0) bcnt[blockIdx.x] = c;
}
__global__ __launch_bounds__(256) void emitN1_k(const int* need, const int* boff,
                                                int* listN1, int* posN) {
  __shared__ int ws4[4];
  int n = blockIdx.x*256 + threadIdx.x;
  int pred = (n < NN) && need[n];
  int rank = blockRank(pred, ws4);
  if (pred) {
    int pos = boff[blockIdx.x] + rank;
    if (pos < CAP_N1) { listN1[pos] = n; posN[n] = pos; }
  }
}

__global__ __launch_bounds__(512) void scan_k(const int* bcnt, int n, int* boff, int* tot) {
  __shared__ int s[512];
  int t = threadIdx.x;
  int orig = (t < n) ? bcnt[t] : 0;
  s[t] = orig;
  __syncthreads();
  for (int o = 1; o < 512; o <<= 1) {
    int v = (t >= o) ? s[t-o] : 0;
    __syncthreads();
    s[t] += v;
    __syncthreads();
  }
  if (t < n) boff[t] = s[t] - orig;
  if (t == n-1) *tot = s[t];
}

__global__ __launch_bounds__(256) void buildw0s_k(const float* W0, float* w0s) {
  int c = blockIdx.x*256 + threadIdx.x;
  if (c >= 512) return;
  const float* row = W0 + (size_t)c*1034;
  w0s[0*512+c] = row[512];  w0s[1*512+c] = row[513];  w0s[2*512+c] = row[514];
  w0s[3*512+c] = row[1027]; w0s[4*512+c] = row[1028]; w0s[5*512+c] = row[1029];
  w0s[6*512+c] = row[1030]; w0s[7*512+c] = row[1031]; w0s[8*512+c] = row[1032];
  w0s[9*512+c] = row[1033];
}

// P0 edge L0 via Ts/Td partial tables (each SK_T partials deep)
__global__ __launch_bounds__(256) void edge0_k(const int* nE0p, const int* listE0,
                                               const int* src, const int* dst,
                                               const float* pbTs, const float* pbTd,
                                               const float* la, const float* w0s,
                                               const float* b0, float* h0c) {
  int i = blockIdx.x;
  int n0 = *nE0p; if (n0 > CAP_E0) n0 = CAP_E0;
  if (i >= n0) return;
  int e = listE0[i];
  int s = src[e], d = dst[e];
  float a0 = la[s*3], a1 = la[s*3+1], a2 = la[s*3+2];
  float c0 = la[d*3], c1 = la[d*3+1], c2 = la[d*3+2];
  float r0 = c0-a0, r1 = c1-a1, r2 = c2-a2;
  float dn = sqrtf(r0*r0 + r1*r1 + r2*r2);
  const float g = LRc / 32.1558704423f; // sqrt(1034)
  int sr = s & 63, dr = d & 63;
  for (int c = threadIdx.x; c < 512; c += 256) {
    float pre = 0.f;
#pragma unroll
    for (int z = 0; z < SK_T; z++) {
      pre += pbTs[((size_t)z*64 + sr)*512 + c];
      pre += pbTd[((size_t)z*64 + dr)*512 + c];
    }
    pre += a0*w0s[0*512+c] + a1*w0s[1*512+c] + a2*w0s[2*512+c]
         + c0*w0s[3*512+c] + c1*w0s[4*512+c] + c2*w0s[5*512+c]
         + r0*w0s[6*512+c] + r1*w0s[7*512+c] + r2*w0s[8*512+c]
         + dn*w0s[9*512+c];
    float y = pre*g + b0[c]*LRc;
    y = (y > 0.f ? y : 0.2f*y) * SQ2;
    h0c[(size_t)i*512 + c] = y;
  }
}

__global__ __launch_bounds__(256) void expand_k(const float* x2, float* out, int total) {
  int i = blockIdx.x*256 + threadIdx.x;
  if (i < total) {
    int d = i & 511;
    int b = i / (14*512);
    out[i] = x2[b*512 + d];
  }
}

extern "C" void kernel_launch(void* const* d_in, const int* in_sizes, int n_in,
                              void* d_out, int out_size, void* d_ws, size_t ws_size,
                              hipStream_t stream) {
  const float* z     = (const float*)d_in[0];
  const float* la    = (const float*)d_in[1];
  const int*   ei    = (const int*)  d_in[2];
  const float* p0ew0 = (const float*)d_in[3];
  const float* p0eb0 = (const float*)d_in[4];
  const float* p0ew1 = (const float*)d_in[5];
  const float* p0eb1 = (const float*)d_in[6];
  const float* p0nw0 = (const float*)d_in[7];
  const float* p0nb0 = (const float*)d_in[8];
  const float* p0nw1 = (const float*)d_in[9];
  const float* p0nb1 = (const float*)d_in[10];
  const float* p1ew0 = (const float*)d_in[11];
  const float* p1eb0 = (const float*)d_in[12];
  const float* p1ew1 = (const float*)d_in[13];
  const float* p1eb1 = (const float*)d_in[14];
  const float* p1nw0 = (const float*)d_in[15];
  const float* p1nb0 = (const float*)d_in[16];
  const float* p1nw1 = (const float*)d_in[17];
  const float* p1nb1 = (const float*)d_in[18];
  const int* src = ei;
  const int* dst = ei + EN;

  char* ws = (char*)d_ws;
  size_t off = 0;
  auto al = [&](size_t bytes) -> void* {
    void* r = (void*)(ws + off);
    off += (bytes + 255) & ~(size_t)255;
    return r;
  };
  // ---- zeroed region (identical context every call) ----
  int*   tot    = (int*)  al(3*4);
  float* cnt    = (float*)al(NN*4);
  int*   need   = (int*)  al(NN*4);
  int*   posN   = (int*)  al(NN*4);
  int*   posOf  = (int*)  al((size_t)EN*4);
  int*   bcntE  = (int*)  al(EBLK*4);
  int*   boffE  = (int*)  al(EBLK*4);
  int*   bcntN  = (int*)  al(NBLK*4);
  int*   boffN  = (int*)  al(NBLK*4);
  int*   listES = (int*)  al(CAP_ES*4);
  int*   listN1 = (int*)  al(CAP_N1*4);
  int*   listE0 = (int*)  al(CAP_E0*4);
  float* agg0c  = (float*)al((size_t)CAP_N1*512*4);   // atomic target: must start 0
  float* agg1c  = (float*)al(64*512*4);               // atomic target: must start 0
  size_t zEnd = off;
  // ---- written-before-read region (proofs in comments at each use) ----
  float* zn     = (float*)al(64*512*4);
  float* w0s    = (float*)al(10*512*4);
  float* pbTs   = (float*)al((size_t)SK_T*64*512*4);
  float* pbTd   = (float*)al((size_t)SK_T*64*512*4);
  float* pbT0   = (float*)al((size_t)SK_T*64*512*4);
  float* x1c    = (float*)al((size_t)CAP_N1*512*4);
  float* h0c    = (float*)al((size_t)CAP_E0*512*4);   // reused: E0 hidden, node hidden, ES hidden
  float* ef0c   = (float*)al((size_t)CAP_E0*512*4);
  float* hn64   = (float*)al(64*512*4);
  float* x2     = (float*)al(64*512*4);
  float* pbuf   = (float*)al((size_t)CAP_E0*512*2*4); // 33.5 MB, max over all SK×Mcap

  hipMemsetAsync(ws, 0, zEnd, stream);

  rms_k<<<64, 256, 0, stream>>>(z, zn);
  initneed_k<<<NBLK, 256, 0, stream>>>(need);
  count_k<<<EBLK, 256, 0, stream>>>(dst, cnt);

  cntES_k<<<EBLK, 256, 0, stream>>>(dst, bcntE);
  scan_k<<<1, 512, 0, stream>>>(bcntE, EBLK, boffE, tot+0);
  emitES_k<<<EBLK, 256, 0, stream>>>(src, dst, boffE, listES, need);

  cntE0_k<<<EBLK, 256, 0, stream>>>(dst, need, bcntE);
  scan_k<<<1, 512, 0, stream>>>(bcntE, EBLK, boffE, tot+1);
  emitE0_k<<<EBLK, 256, 0, stream>>>(dst, need, boffE, listE0, posOf);

  cntN1_k<<<NBLK, 256, 0, stream>>>(need, bcntN);
  scan_k<<<1, 512, 0, stream>>>(bcntN, NBLK, boffN, tot+2);
  emitN1_k<<<NBLK, 256, 0, stream>>>(need, boffN, listN1, posN);

  buildw0s_k<<<2, 256, 0, stream>>>(p0ew0, w0s);

  // Ts/Td/T0 tables as split-K partials (M=64, K=512, SK_T=4, KC=128)
  {
    GPP p{}; p.K = 512; p.KC = 128; p.Mcap = 64; p.Mfix = 64; p.Mdev = nullptr;
    p.Ain = zn;
    p.W = p0ew0; p.Wld = 1034; p.Woff = 0;   p.pbuf = pbTs;
    gemmP<0><<<dim3(2, 8, SK_T), 256, 0, stream>>>(p);
    p.Woff = 515; p.pbuf = pbTd;
    gemmP<0><<<dim3(2, 8, SK_T), 256, 0, stream>>>(p);
    p.W = p0nw0; p.Wld = 1030; p.Woff = 0;   p.pbuf = pbT0;
    gemmP<0><<<dim3(2, 8, SK_T), 256, 0, stream>>>(p);
  }

  // P0 edge L0 (tables) -> h0c  [h0c rows < nE0 written here, read below with r < nE0]
  edge0_k<<<CAP_E0, 256, 0, stream>>>(tot+1, listE0, src, dst, pbTs, pbTd, la, w0s, p0eb0, h0c);

  // P0 edge L1: K=512, SK=2 -> ef0c + atomic agg0c
  {
    GPP p{}; p.W = p0ew1; p.Wld = 512; p.Woff = 0; p.K = 512; p.KC = 256;
    p.Mcap = CAP_E0; p.Mdev = tot+1; p.Ain = h0c; p.pbuf = pbuf;
    gemmP<0><<<dim3(CAP_E0/32, 8, 2), 256, 0, stream>>>(p);
    EPP e{}; e.pbuf = pbuf; e.SK = 2; e.Mcap = CAP_E0; e.Mdev = tot+1;
    e.bias = p0eb1; e.gain = LRc/sqrtf(512.f);
    e.rmap = listE0; e.dst = dst; e.posN = posN; e.outp = ef0c; e.atomp = agg0c;
    epi_k<1><<<(CAP_E0*512)/256, 256, 0, stream>>>(e);
  }
  // P0 node L0: K=518 (la|la'|agg0c), SK=4, + T0 table in epilogue -> h0c (reuse)
  {
    GPP p{}; p.W = p0nw0; p.Wld = 1030; p.Woff = 512; p.K = 518; p.KC = 160;
    p.Mcap = CAP_N1; p.Mdev = tot+2; p.rmap = listN1;
    p.la = la; p.cnt = cnt; p.agg = agg0c; p.pbuf = pbuf;
    gemmP<2><<<dim3(CAP_N1/32, 8, 4), 256, 0, stream>>>(p);
    EPP e{}; e.pbuf = pbuf; e.SK = 4; e.Mcap = CAP_N1; e.Mdev = tot+2;
    e.bias = p0nb0; e.gain = LRc/sqrtf(1030.f);
    e.T0p = pbT0; e.rmap = listN1; e.outp = h0c;
    epi_k<7><<<(CAP_N1*512)/256, 256, 0, stream>>>(e);
  }
  // P0 node L1: K=512, SK=4 -> x1c (compact store)
  {
    GPP p{}; p.W = p0nw1; p.Wld = 512; p.Woff = 0; p.K = 512; p.KC = 128;
    p.Mcap = CAP_N1; p.Mdev = tot+2; p.Ain = h0c; p.pbuf = pbuf;
    gemmP<0><<<dim3(CAP_N1/32, 8, 4), 256, 0, stream>>>(p);
    EPP e{}; e.pbuf = pbuf; e.SK = 4; e.Mcap = CAP_N1; e.Mdev = tot+2;
    e.bias = p0nb1; e.gain = LRc/sqrtf(512.f); e.outp = x1c;
    epi_k<0><<<(CAP_N1*512)/256, 256, 0, stream>>>(e);
  }
  // P1 edge L0: K=1536, SK=6 -> h0c (reuse)
  {
    GPP p{}; p.W = p1ew0; p.Wld = 1536; p.Woff = 0; p.K = 1536; p.KC = 256;
    p.Mcap = CAP_ES; p.Mdev = tot+0; p.rmap = listES;
    p.x1 = x1c; p.ef0 = ef0c; p.posOf = posOf; p.posN = posN;
    p.src = src; p.dst = dst; p.pbuf = pbuf;
    gemmP<3><<<dim3(CAP_ES/32, 8, 6), 256, 0, stream>>>(p);
    EPP e{}; e.pbuf = pbuf; e.SK = 6; e.Mcap = CAP_ES; e.Mdev = tot+0;
    e.bias = p1eb0; e.gain = LRc/sqrtf(1536.f); e.outp = h0c;
    epi_k<0><<<(CAP_ES*512)/256, 256, 0, stream>>>(e);
  }
  // P1 edge L1: K=512, SK=4 -> atomic agg1c
  {
    GPP p{}; p.W = p1ew1; p.Wld = 512; p.Woff = 0; p.K = 512; p.KC = 128;
    p.Mcap = CAP_ES; p.Mdev = tot+0; p.Ain = h0c; p.pbuf = pbuf;
    gemmP<0><<<dim3(CAP_ES/32, 8, 4), 256, 0, stream>>>(p);
    EPP e{}; e.pbuf = pbuf; e.SK = 4; e.Mcap = CAP_ES; e.Mdev = tot+0;
    e.bias = p1eb1; e.gain = LRc/sqrtf(512.f);
    e.rmap = listES; e.dst = dst; e.atomp = agg1c;
    epi_k<2><<<(CAP_ES*512)/256, 256, 0, stream>>>(e);
  }
  // P1 node L0: K=1024, SK=8 -> hn64
  {
    GPP p{}; p.W = p1nw0; p.Wld = 1024; p.Woff = 0; p.K = 1024; p.KC = 128;
    p.Mcap = 64; p.Mfix = 64; p.Mdev = nullptr;
    p.x1 = x1c; p.posN = posN; p.agg = agg1c; p.cnt = cnt; p.pbuf = pbuf;
    gemmP<4><<<dim3(2, 8, 8), 256, 0, stream>>>(p);
    EPP e{}; e.pbuf = pbuf; e.SK = 8; e.Mcap = 64; e.Mfix = 64;
    e.bias = p1nb0; e.gain = LRc/sqrtf(1024.f); e.outp = hn64;
    epi_k<0><<<(64*512)/256, 256, 0, stream>>>(e);
  }
  // P1 node L1: K=512, SK=4 -> x2
  {
    GPP p{}; p.W = p1nw1; p.Wld = 512; p.Woff = 0; p.K = 512; p.KC = 128;
    p.Mcap = 64; p.Mfix = 64; p.Mdev = nullptr; p.Ain = hn64; p.pbuf = pbuf;
    gemmP<0><<<dim3(2, 8, 4), 256, 0, stream>>>(p);
    EPP e{}; e.pbuf = pbuf; e.SK = 4; e.Mcap = 64; e.Mfix = 64;
    e.bias = p1nb1; e.gain = LRc/sqrtf(512.f); e.outp = x2;
    epi_k<0><<<(64*512)/256, 256, 0, stream>>>(e);
  }
  expand_k<<<(64*14*512+255)/256, 256, 0, stream>>>(x2, (float*)d_out, 64*14*512);
}

// Round 5
// 306.120 us; speedup vs baseline: 60.7870x; 1.3402x over previous
//
#include <hip/hip_runtime.h>
#include <hip/hip_bf16.h>
#include <cmath>

#define NVP 250
#define NN  16000
#define EN  95232
#define LRc 0.01f
#define SQ2 1.41421356237309515f

#define CAP_ES 1024
#define CAP_N1 2048
#define CAP_E0 8192
#define EBLK ((EN + 255) / 256)   // 372
#define NBLK ((NN + 255) / 256)   // 63
#define SK_T 4

struct GPP {
  const float* W; const float* Ain; float* pbuf; const int* Mdev;
  int Wld, Woff, K, KC, Mcap, Mfix;
};

// Dense split-K partial GEMM. BM=32, BN=64, BK=32. A stride == K.
// pbuf[z][m][n] = sum_{k in [z*KC, min(K,(z+1)*KC))} A[m][k] * W[n][Woff+k]
template<int VECW>
__global__ __launch_bounds__(256) void gemmP(GPP p) {
  int M = p.Mdev ? *p.Mdev : p.Mfix;
  if (M > p.Mcap) M = p.Mcap;
  const int mBase = blockIdx.x * 32;
  if (mBase >= M) return;
  const int nBase = blockIdx.y * 64;
  const int z = blockIdx.z;
  const int kBeg = z * p.KC;
  int kEnd = kBeg + p.KC; if (kEnd > p.K) kEnd = p.K;

  __shared__ float As[32][36];   // [mr][kk], b128-writable
  __shared__ float Bs[32][65];   // [kk][nr]
  const int t = threadIdx.x;
  const int tx = t & 15, ty = t >> 4;
  const int amr = t >> 3, ak4 = t & 7;

  float acc[2][4] = {};
  for (int k0 = kBeg; k0 < kEnd; k0 += 32) {
    // stage A: one float4 per thread
    float4 av = make_float4(0.f, 0.f, 0.f, 0.f);
    int ar = mBase + amr;
    if (ar < M) av = *(const float4*)&p.Ain[(size_t)ar * p.K + k0 + ak4*4];
    *(float4*)&As[amr][ak4*4] = av;
    // stage B: two float4 (or 2x4 scalar) per thread, transposed into Bs
#pragma unroll
    for (int h = 0; h < 2; h++) {
      int idx = t*2 + h;
      int nr = idx >> 3, k4 = idx & 7;
      const float* wr = p.W + (size_t)(nBase + nr) * p.Wld + p.Woff + k0 + k4*4;
      if (VECW) {
        float4 wv = *(const float4*)wr;
        Bs[k4*4+0][nr] = wv.x; Bs[k4*4+1][nr] = wv.y;
        Bs[k4*4+2][nr] = wv.z; Bs[k4*4+3][nr] = wv.w;
      } else {
        Bs[k4*4+0][nr] = wr[0]; Bs[k4*4+1][nr] = wr[1];
        Bs[k4*4+2][nr] = wr[2]; Bs[k4*4+3][nr] = wr[3];
      }
    }
    __syncthreads();
#pragma unroll
    for (int kk = 0; kk < 32; kk++) {
      float a0 = As[ty*2+0][kk], a1 = As[ty*2+1][kk];
      float b0 = Bs[kk][tx*4+0], b1 = Bs[kk][tx*4+1];
      float b2 = Bs[kk][tx*4+2], b3 = Bs[kk][tx*4+3];
      acc[0][0] += a0*b0; acc[0][1] += a0*b1; acc[0][2] += a0*b2; acc[0][3] += a0*b3;
      acc[1][0] += a1*b0; acc[1][1] += a1*b1; acc[1][2] += a1*b2; acc[1][3] += a1*b3;
    }
    __syncthreads();
  }
#pragma unroll
  for (int i = 0; i < 2; i++) {
    int r = mBase + ty*2 + i;
    float4 v = make_float4(acc[i][0], acc[i][1], acc[i][2], acc[i][3]);
    *(float4*)&p.pbuf[((size_t)z * p.Mcap + r)*512 + nBase + tx*4] = v;
  }
}

struct EPP {
  const float* pbuf; const float* bias; const float* T0p; const float* la;
  const float* cnt; const float* w0n;
  const int* rmap; const int* dst; const int* posN; const int* Mdev;
  float* outp; float* atomp;
  int SK, Mcap, Mfix; float gain;
};

// EPI 0: store outp[m]. EPI 1: store + atomicAdd agg0c[posN[dst[rmap[m]]]].
// EPI 2: atomicAdd agg1c[dst[rmap[m]]/250]. EPI 7: +T0 +la*w0n correction, store.
// EPI 8: store 14x tiled to d_out.
template<int EPI>
__global__ __launch_bounds__(256) void epi_k(EPP e) {
  int M = e.Mdev ? *e.Mdev : e.Mfix;
  if (M > e.Mcap) M = e.Mcap;
  int i = blockIdx.x*256 + threadIdx.x;   // float4 index
  if (i >= M*128) return;
  int m = i >> 7, n4 = (i & 127) * 4;
  float ys[4] = {0.f, 0.f, 0.f, 0.f};
  for (int z = 0; z < e.SK; z++) {
    float4 v = *(const float4*)&e.pbuf[((size_t)z*e.Mcap + m)*512 + n4];
    ys[0] += v.x; ys[1] += v.y; ys[2] += v.z; ys[3] += v.w;
  }
  if (EPI == 7) {
    int nd = e.rmap[m];
    int rr = nd & 63;
#pragma unroll
    for (int z = 0; z < SK_T; z++) {
      float4 v = *(const float4*)&e.T0p[((size_t)z*64 + rr)*512 + n4];
      ys[0] += v.x; ys[1] += v.y; ys[2] += v.z; ys[3] += v.w;
    }
    float l0 = e.la[nd*3], l1 = e.la[nd*3+1], l2 = e.la[nd*3+2];
    bool has = e.cnt[nd] > 0.f;
#pragma unroll
    for (int j = 0; j < 4; j++) {
      int n = n4 + j;
      float corr = l0*e.w0n[0*512+n] + l1*e.w0n[1*512+n] + l2*e.w0n[2*512+n];
      if (has) corr += l0*e.w0n[3*512+n] + l1*e.w0n[4*512+n] + l2*e.w0n[5*512+n];
      ys[j] += corr;
    }
  }
#pragma unroll
  for (int j = 0; j < 4; j++) {
    float y = ys[j] * e.gain + e.bias[n4+j] * LRc;
    ys[j] = (y > 0.f ? y : 0.2f*y) * SQ2;
  }
  float4 ov = make_float4(ys[0], ys[1], ys[2], ys[3]);
  if (EPI == 0 || EPI == 7) {
    *(float4*)&e.outp[(size_t)m*512 + n4] = ov;
  } else if (EPI == 1) {
    *(float4*)&e.outp[(size_t)m*512 + n4] = ov;
    int tr = e.posN[e.dst[e.rmap[m]]];
#pragma unroll
    for (int j = 0; j < 4; j++) atomicAdd(&e.atomp[(size_t)tr*512 + n4 + j], ys[j]);
  } else if (EPI == 2) {
    int tr = e.dst[e.rmap[m]] / NVP;
#pragma unroll
    for (int j = 0; j < 4; j++) atomicAdd(&e.atomp[(size_t)tr*512 + n4 + j], ys[j]);
  } else { // 8
#pragma unroll
    for (int w = 0; w < 14; w++)
      *(float4*)&e.outp[((size_t)(m*14 + w))*512 + n4] = ov;
  }
}

__global__ __launch_bounds__(256) void rms_k(const float* z, float* zn) {
  int b = blockIdx.x, t = threadIdx.x;
  float s = 0.f;
  for (int j = t; j < 512; j += 256) { float v = z[b*512+j]; s += v*v; }
  for (int o = 32; o > 0; o >>= 1) s += __shfl_down(s, o);
  __shared__ float red[5];
  if ((t & 63) == 0) red[t >> 6] = s;
  __syncthreads();
  if (t == 0) {
    float tot = red[0]+red[1]+red[2]+red[3];
    red[4] = 1.0f / sqrtf(tot * (1.0f/512.0f) + 1e-8f);
  }
  __syncthreads();
  float r = red[4];
  for (int j = t; j < 512; j += 256) zn[b*512+j] = z[b*512+j] * r;
}

__global__ __launch_bounds__(256) void initneed_k(int* need) {
  int n = blockIdx.x*256 + threadIdx.x;
  if (n < NN) need[n] = ((n % NVP) == 0) ? 1 : 0;
}

// ---- deterministic compaction ----
__device__ __forceinline__ int blockCount(int pred, int* ws4) {
  unsigned long long m = __ballot(pred);
  int lane = threadIdx.x & 63, w = threadIdx.x >> 6;
  if (lane == 0) ws4[w] = __popcll(m);
  __syncthreads();
  return ws4[0] + ws4[1] + ws4[2] + ws4[3];
}
__device__ __forceinline__ int blockRank(int pred, int* ws4) {
  unsigned long long m = __ballot(pred);
  int lane = threadIdx.x & 63, w = threadIdx.x >> 6;
  if (lane == 0) ws4[w] = __popcll(m);
  __syncthreads();
  int off = 0;
  for (int i = 0; i < w; i++) off += ws4[i];
  return off + __popcll(m & ((1ull << lane) - 1ull));
}

// also does cnt accumulation (integer-valued atomics: exact, order-free)
__global__ __launch_bounds__(256) void cntES_k(const int* dst, float* cnt, int* bcnt) {
  __shared__ int ws4[4];
  int e = blockIdx.x*256 + threadIdx.x;
  int pred = 0;
  if (e < EN) {
    int d = dst[e];
    atomicAdd(&cnt[d], 1.0f);
    pred = (d % NVP) == 0;
  }
  int c = blockCount(pred, ws4);
  if (threadIdx.x == 0) bcnt[blockIdx.x] = c;
}
__global__ __launch_bounds__(256) void emitES_k(const int* src, const int* dst,
                                                const int* boff, int* listES, int* need) {
  __shared__ int ws4[4];
  int e = blockIdx.x*256 + threadIdx.x;
  int pred = (e < EN) && (dst[e] % NVP == 0);
  int rank = blockRank(pred, ws4);
  if (pred) {
    int pos = boff[blockIdx.x] + rank;
    if (pos < CAP_ES) listES[pos] = e;
    need[src[e]] = 1;
  }
}
__global__ __launch_bounds__(256) void cntE0_k(const int* dst, const int* need, int* bcnt) {
  __shared__ int ws4[4];
  int e = blockIdx.x*256 + threadIdx.x;
  int pred = (e < EN) && need[dst[e]];
  int c = blockCount(pred, ws4);
  if (threadIdx.x == 0) bcnt[blockIdx.x] = c;
}
__global__ __launch_bounds__(256) void emitE0_k(const int* dst, const int* need,
                                                const int* boff, int* listE0, int* posOf) {
  __shared__ int ws4[4];
  int e = blockIdx.x*256 + threadIdx.x;
  int pred = (e < EN) && need[dst[e]];
  int rank = blockRank(pred, ws4);
  if (pred) {
    int pos = boff[blockIdx.x] + rank;
    if (pos < CAP_E0) { listE0[pos] = e; posOf[e] = pos; }
  }
}
__global__ __launch_bounds__(256) void cntN1_k(const int* need, int* bcnt) {
  __shared__ int ws4[4];
  int n = blockIdx.x*256 + threadIdx.x;
  int pred = (n < NN) && need[n];
  int c = blockCount(pred, ws4);
  if (threadIdx.x == 0) bcnt[blockIdx.x] = c;
}
__global__ __launch_bounds__(256) void emitN1_k(const int* need, const int* boff,
                                                int* listN1, int* posN) {
  __shared__ int ws4[4];
  int n = blockIdx.x*256 + threadIdx.x;
  int pred = (n < NN) && need[n];
  int rank = blockRank(pred, ws4);
  if (pred) {
    int pos = boff[blockIdx.x] + rank;
    if (pos < CAP_N1) { listN1[pos] = n; posN[n] = pos; }
  }
}

__global__ __launch_bounds__(512) void scan_k(const int* bcnt, int n, int* boff, int* tot) {
  __shared__ int s[512];
  int t = threadIdx.x;
  int orig = (t < n) ? bcnt[t] : 0;
  s[t] = orig;
  __syncthreads();
  for (int o = 1; o < 512; o <<= 1) {
    int v = (t >= o) ? s[t-o] : 0;
    __syncthreads();
    s[t] += v;
    __syncthreads();
  }
  if (t < n) boff[t] = s[t] - orig;
  if (t == n-1) *tot = s[t];
}

__global__ __launch_bounds__(256) void rows_k(const int* nESp, const int* listES,
                                              const int* src, const int* dst,
                                              const int* posN, const int* posOf,
                                              int* rowS, int* rowD, int* rowE) {
  int n = *nESp; if (n > CAP_ES) n = CAP_ES;
  int i = blockIdx.x*256 + threadIdx.x;
  if (i >= n) return;
  int e = listES[i];
  rowS[i] = posN[src[e]];
  rowD[i] = posN[dst[e]];
  rowE[i] = posOf[e];
}

// w0s: 10 small cols of p0ew0 transposed; w0n: 6 small cols of p0nw0 transposed
__global__ __launch_bounds__(256) void buildw_k(const float* W0, const float* Wn,
                                                float* w0s, float* w0n) {
  int c = blockIdx.x*256 + threadIdx.x;
  if (c >= 512) return;
  const float* row = W0 + (size_t)c*1034;
  w0s[0*512+c] = row[512];  w0s[1*512+c] = row[513];  w0s[2*512+c] = row[514];
  w0s[3*512+c] = row[1027]; w0s[4*512+c] = row[1028]; w0s[5*512+c] = row[1029];
  w0s[6*512+c] = row[1030]; w0s[7*512+c] = row[1031]; w0s[8*512+c] = row[1032];
  w0s[9*512+c] = row[1033];
  const float* rn = Wn + (size_t)c*1030;
#pragma unroll
  for (int j = 0; j < 6; j++) w0n[j*512+c] = rn[512+j];
}

// P0 edge L0 via Ts/Td partial tables, float4
__global__ __launch_bounds__(256) void edge0_k(const int* nE0p, const int* listE0,
                                               const int* src, const int* dst,
                                               const float* pbTs, const float* pbTd,
                                               const float* la, const float* w0s,
                                               const float* b0, float* h0c) {
  int i = blockIdx.x;
  int n0 = *nE0p; if (n0 > CAP_E0) n0 = CAP_E0;
  if (i >= n0) return;
  int tid = threadIdx.x;
  if (tid >= 128) return;
  int e = listE0[i];
  int s = src[e], d = dst[e];
  float a0 = la[s*3], a1 = la[s*3+1], a2 = la[s*3+2];
  float c0 = la[d*3], c1 = la[d*3+1], c2 = la[d*3+2];
  float r0 = c0-a0, r1 = c1-a1, r2 = c2-a2;
  float dn = sqrtf(r0*r0 + r1*r1 + r2*r2);
  const float g = LRc / 32.1558704423f; // sqrt(1034)
  int sr = s & 63, dr = d & 63;
  int c4 = tid*4;
  float ys[4] = {0.f,0.f,0.f,0.f};
#pragma unroll
  for (int z = 0; z < SK_T; z++) {
    float4 vs = *(const float4*)&pbTs[((size_t)z*64 + sr)*512 + c4];
    float4 vd = *(const float4*)&pbTd[((size_t)z*64 + dr)*512 + c4];
    ys[0] += vs.x + vd.x; ys[1] += vs.y + vd.y;
    ys[2] += vs.z + vd.z; ys[3] += vs.w + vd.w;
  }
  float cf[10] = {a0,a1,a2,c0,c1,c2,r0,r1,r2,dn};
#pragma unroll
  for (int j = 0; j < 10; j++) {
    float4 wv = *(const float4*)&w0s[j*512 + c4];
    ys[0] += cf[j]*wv.x; ys[1] += cf[j]*wv.y; ys[2] += cf[j]*wv.z; ys[3] += cf[j]*wv.w;
  }
  float4 bv = *(const float4*)&b0[c4];
  float bb[4] = {bv.x, bv.y, bv.z, bv.w};
#pragma unroll
  for (int j = 0; j < 4; j++) {
    float y = ys[j]*g + bb[j]*LRc;
    ys[j] = (y > 0.f ? y : 0.2f*y) * SQ2;
  }
  *(float4*)&h0c[(size_t)i*512 + c4] = make_float4(ys[0],ys[1],ys[2],ys[3]);
}

__global__ __launch_bounds__(256) void scaleAgg0_k(const int* nN1p, const int* listN1,
                                                   const float* cnt, float* agg0c) {
  int n1 = *nN1p; if (n1 > CAP_N1) n1 = CAP_N1;
  int i = blockIdx.x*256 + threadIdx.x;
  if (i >= n1*128) return;
  int m = i >> 7;
  float rinv = 1.0f / fmaxf(cnt[listN1[m]], 1.0f);
  float4* pp = (float4*)&agg0c[(size_t)m*512 + (i & 127)*4];
  float4 v = *pp;
  v.x *= rinv; v.y *= rinv; v.z *= rinv; v.w *= rinv;
  *pp = v;
}

__global__ __launch_bounds__(256) void buildAes_k(const int* nESp, const int* rowS,
                                                  const int* rowD, const int* rowE,
                                                  const float* x1c, const float* ef0c,
                                                  float* Aes) {
  int i = blockIdx.x;
  int n = *nESp; if (n > CAP_ES) n = CAP_ES;
  if (i >= n) return;
  int rs = rowS[i], rd = rowD[i], re = rowE[i];
  for (int q = threadIdx.x; q < 384; q += 256) {
    int seg = q >> 7, w = (q & 127)*4;
    const float* sp = (seg == 0) ? &x1c[(size_t)rs*512 + w]
                    : (seg == 1) ? &x1c[(size_t)rd*512 + w]
                                 : &ef0c[(size_t)re*512 + w];
    *(float4*)&Aes[(size_t)i*1536 + q*4] = *(const float4*)sp;
  }
}

__global__ __launch_bounds__(256) void buildA64_k(const int* posN, const float* x1c,
                                                  const float* agg1c, const float* cnt,
                                                  float* A64) {
  int m = blockIdx.x;
  int q = threadIdx.x;
  if (q < 128) {
    *(float4*)&A64[(size_t)m*1024 + q*4] =
      *(const float4*)&x1c[(size_t)posN[m*NVP]*512 + q*4];
  } else {
    float rinv = 1.0f / fmaxf(cnt[m*NVP], 1.0f);
    int w = (q - 128)*4;
    float4 v = *(const float4*)&agg1c[(size_t)m*512 + w];
    v.x *= rinv; v.y *= rinv; v.z *= rinv; v.w *= rinv;
    *(float4*)&A64[(size_t)m*1024 + 512 + w] = v;
  }
}

extern "C" void kernel_launch(void* const* d_in, const int* in_sizes, int n_in,
                              void* d_out, int out_size, void* d_ws, size_t ws_size,
                              hipStream_t stream) {
  const float* z     = (const float*)d_in[0];
  const float* la    = (const float*)d_in[1];
  const int*   ei    = (const int*)  d_in[2];
  const float* p0ew0 = (const float*)d_in[3];
  const float* p0eb0 = (const float*)d_in[4];
  const float* p0ew1 = (const float*)d_in[5];
  const float* p0eb1 = (const float*)d_in[6];
  const float* p0nw0 = (const float*)d_in[7];
  const float* p0nb0 = (const float*)d_in[8];
  const float* p0nw1 = (const float*)d_in[9];
  const float* p0nb1 = (const float*)d_in[10];
  const float* p1ew0 = (const float*)d_in[11];
  const float* p1eb0 = (const float*)d_in[12];
  const float* p1ew1 = (const float*)d_in[13];
  const float* p1eb1 = (const float*)d_in[14];
  const float* p1nw0 = (const float*)d_in[15];
  const float* p1nb0 = (const float*)d_in[16];
  const float* p1nw1 = (const float*)d_in[17];
  const float* p1nb1 = (const float*)d_in[18];
  const int* src = ei;
  const int* dst = ei + EN;

  char* ws = (char*)d_ws;
  size_t off = 0;
  auto al = [&](size_t bytes) -> void* {
    void* r = (void*)(ws + off);
    off += (bytes + 255) & ~(size_t)255;
    return r;
  };
  // ---- zeroed region ----
  int*   tot    = (int*)  al(3*4);
  float* cnt    = (float*)al(NN*4);
  int*   need   = (int*)  al(NN*4);
  int*   posN   = (int*)  al(NN*4);
  int*   posOf  = (int*)  al((size_t)EN*4);
  int*   bcntE  = (int*)  al(EBLK*4);
  int*   boffE  = (int*)  al(EBLK*4);
  int*   bcntN  = (int*)  al(NBLK*4);
  int*   boffN  = (int*)  al(NBLK*4);
  int*   listES = (int*)  al(CAP_ES*4);
  int*   listN1 = (int*)  al(CAP_N1*4);
  int*   listE0 = (int*)  al(CAP_E0*4);
  float* agg0c  = (float*)al((size_t)CAP_N1*512*4);
  float* agg1c  = (float*)al(64*512*4);
  size_t zEnd = off;
  // ---- written-before-read region ----
  int*   rowS   = (int*)  al(CAP_ES*4);
  int*   rowD   = (int*)  al(CAP_ES*4);
  int*   rowE   = (int*)  al(CAP_ES*4);
  float* zn     = (float*)al(64*512*4);
  float* w0s    = (float*)al(10*512*4);
  float* w0n    = (float*)al(6*512*4);
  float* pbTs   = (float*)al((size_t)SK_T*64*512*4);
  float* pbTd   = (float*)al((size_t)SK_T*64*512*4);
  float* pbT0   = (float*)al((size_t)SK_T*64*512*4);
  float* h0c    = (float*)al((size_t)CAP_E0*512*4);
  float* ef0c   = (float*)al((size_t)CAP_E0*512*4);
  float* hn1    = (float*)al((size_t)CAP_N1*512*4);
  float* x1c    = (float*)al((size_t)CAP_N1*512*4);
  float* Aes    = (float*)al((size_t)CAP_ES*1536*4);
  float* hs     = (float*)al((size_t)CAP_ES*512*4);
  float* A64    = (float*)al(64*1024*4);
  float* hn64   = (float*)al(64*512*4);
  float* pbuf   = (float*)al((size_t)CAP_E0*512*2*4);

  hipMemsetAsync(ws, 0, zEnd, stream);

  rms_k<<<64, 256, 0, stream>>>(z, zn);
  initneed_k<<<NBLK, 256, 0, stream>>>(need);

  cntES_k<<<EBLK, 256, 0, stream>>>(dst, cnt, bcntE);
  scan_k<<<1, 512, 0, stream>>>(bcntE, EBLK, boffE, tot+0);
  emitES_k<<<EBLK, 256, 0, stream>>>(src, dst, boffE, listES, need);

  cntE0_k<<<EBLK, 256, 0, stream>>>(dst, need, bcntE);
  scan_k<<<1, 512, 0, stream>>>(bcntE, EBLK, boffE, tot+1);
  emitE0_k<<<EBLK, 256, 0, stream>>>(dst, need, boffE, listE0, posOf);

  cntN1_k<<<NBLK, 256, 0, stream>>>(need, bcntN);
  scan_k<<<1, 512, 0, stream>>>(bcntN, NBLK, boffN, tot+2);
  emitN1_k<<<NBLK, 256, 0, stream>>>(need, boffN, listN1, posN);

  rows_k<<<CAP_ES/256, 256, 0, stream>>>(tot+0, listES, src, dst, posN, posOf,
                                         rowS, rowD, rowE);
  buildw_k<<<2, 256, 0, stream>>>(p0ew0, p0nw0, w0s, w0n);

  // Ts/Td/T0 tables (M=64, K=512, SK_T partials)
  {
    GPP p{}; p.K = 512; p.KC = 128; p.Mcap = 64; p.Mfix = 64; p.Mdev = nullptr;
    p.Ain = zn;
    p.W = p0ew0; p.Wld = 1034; p.Woff = 0;   p.pbuf = pbTs;
    gemmP<0><<<dim3(2, 8, SK_T), 256, 0, stream>>>(p);
    p.Woff = 515; p.pbuf = pbTd;
    gemmP<0><<<dim3(2, 8, SK_T), 256, 0, stream>>>(p);
    p.W = p0nw0; p.Wld = 1030; p.Woff = 0;   p.pbuf = pbT0;
    gemmP<0><<<dim3(2, 8, SK_T), 256, 0, stream>>>(p);
  }

  edge0_k<<<CAP_E0, 256, 0, stream>>>(tot+1, listE0, src, dst, pbTs, pbTd, la, w0s,
                                      p0eb0, h0c);

  // P0 edge L1: dense, K=512, SK=2 -> ef0c + atomic agg0c
  {
    GPP p{}; p.W = p0ew1; p.Wld = 512; p.Woff = 0; p.K = 512; p.KC = 256;
    p.Mcap = CAP_E0; p.Mdev = tot+1; p.Ain = h0c; p.pbuf = pbuf;
    gemmP<1><<<dim3(CAP_E0/32, 8, 2), 256, 0, stream>>>(p);
    EPP e{}; e.pbuf = pbuf; e.SK = 2; e.Mcap = CAP_E0; e.Mdev = tot+1;
    e.bias = p0eb1; e.gain = LRc/sqrtf(512.f);
    e.rmap = listE0; e.dst = dst; e.posN = posN; e.outp = ef0c; e.atomp = agg0c;
    epi_k<1><<<(CAP_E0*128)/256, 256, 0, stream>>>(e);
  }
  scaleAgg0_k<<<(CAP_N1*128)/256, 256, 0, stream>>>(tot+2, listN1, cnt, agg0c);

  // P0 node L0: dense over scaled agg0c (K=512, W cols 518..1029) + epi7
  {
    GPP p{}; p.W = p0nw0; p.Wld = 1030; p.Woff = 518; p.K = 512; p.KC = 128;
    p.Mcap = CAP_N1; p.Mdev = tot+2; p.Ain = agg0c; p.pbuf = pbuf;
    gemmP<0><<<dim3(CAP_N1/32, 8, 4), 256, 0, stream>>>(p);
    EPP e{}; e.pbuf = pbuf; e.SK = 4; e.Mcap = CAP_N1; e.Mdev = tot+2;
    e.bias = p0nb0; e.gain = LRc/sqrtf(1030.f);
    e.T0p = pbT0; e.rmap = listN1; e.la = la; e.cnt = cnt; e.w0n = w0n; e.outp = hn1;
    epi_k<7><<<(CAP_N1*128)/256, 256, 0, stream>>>(e);
  }
  // P0 node L1 -> x1c
  {
    GPP p{}; p.W = p0nw1; p.Wld = 512; p.Woff = 0; p.K = 512; p.KC = 128;
    p.Mcap = CAP_N1; p.Mdev = tot+2; p.Ain = hn1; p.pbuf = pbuf;
    gemmP<1><<<dim3(CAP_N1/32, 8, 4), 256, 0, stream>>>(p);
    EPP e{}; e.pbuf = pbuf; e.SK = 4; e.Mcap = CAP_N1; e.Mdev = tot+2;
    e.bias = p0nb1; e.gain = LRc/sqrtf(512.f); e.outp = x1c;
    epi_k<0><<<(CAP_N1*128)/256, 256, 0, stream>>>(e);
  }
  buildAes_k<<<CAP_ES, 256, 0, stream>>>(tot+0, rowS, rowD, rowE, x1c, ef0c, Aes);

  // P1 edge L0: dense K=1536, SK=6 -> hs
  {
    GPP p{}; p.W = p1ew0; p.Wld = 1536; p.Woff = 0; p.K = 1536; p.KC = 256;
    p.Mcap = CAP_ES; p.Mdev = tot+0; p.Ain = Aes; p.pbuf = pbuf;
    gemmP<1><<<dim3(CAP_ES/32, 8, 6), 256, 0, stream>>>(p);
    EPP e{}; e.pbuf = pbuf; e.SK = 6; e.Mcap = CAP_ES; e.Mdev = tot+0;
    e.bias = p1eb0; e.gain = LRc/sqrtf(1536.f); e.outp = hs;
    epi_k<0><<<(CAP_ES*128)/256, 256, 0, stream>>>(e);
  }
  // P1 edge L1: dense K=512, SK=4 -> atomic agg1c
  {
    GPP p{}; p.W = p1ew1; p.Wld = 512; p.Woff = 0; p.K = 512; p.KC = 128;
    p.Mcap = CAP_ES; p.Mdev = tot+0; p.Ain = hs; p.pbuf = pbuf;
    gemmP<1><<<dim3(CAP_ES/32, 8, 4), 256, 0, stream>>>(p);
    EPP e{}; e.pbuf = pbuf; e.SK = 4; e.Mcap = CAP_ES; e.Mdev = tot+0;
    e.bias = p1eb1; e.gain = LRc/sqrtf(512.f);
    e.rmap = listES; e.dst = dst; e.atomp = agg1c;
    epi_k<2><<<(CAP_ES*128)/256, 256, 0, stream>>>(e);
  }
  buildA64_k<<<64, 256, 0, stream>>>(posN, x1c, agg1c, cnt, A64);

  // P1 node L0: dense K=1024, SK=8 -> hn64
  {
    GPP p{}; p.W = p1nw0; p.Wld = 1024; p.Woff = 0; p.K = 1024; p.KC = 128;
    p.Mcap = 64; p.Mfix = 64; p.Mdev = nullptr; p.Ain = A64; p.pbuf = pbuf;
    gemmP<1><<<dim3(2, 8, 8), 256, 0, stream>>>(p);
    EPP e{}; e.pbuf = pbuf; e.SK = 8; e.Mcap = 64; e.Mfix = 64;
    e.bias = p1nb0; e.gain = LRc/sqrtf(1024.f); e.outp = hn64;
    epi_k<0><<<(64*128)/256, 256, 0, stream>>>(e);
  }
  // P1 node L1: dense K=512, SK=4 -> d_out (14x tiled)
  {
    GPP p{}; p.W = p1nw1; p.Wld = 512; p.Woff = 0; p.K = 512; p.KC = 128;
    p.Mcap = 64; p.Mfix = 64; p.Mdev = nullptr; p.Ain = hn64; p.pbuf = pbuf;
    gemmP<1><<<dim3(2, 8, 4), 256, 0, stream>>>(p);
    EPP e{}; e.pbuf = pbuf; e.SK = 4; e.Mcap = 64; e.Mfix = 64;
    e.bias = p1nb1; e.gain = LRc/sqrtf(512.f); e.outp = (float*)d_out;
    epi_k<8><<<(64*128)/256, 256, 0, stream>>>(e);
  }
}

// Round 6
// 260.339 us; speedup vs baseline: 71.4765x; 1.1759x over previous
//
#include <hip/hip_runtime.h>
#include <hip/hip_bf16.h>
#include <cmath>

#define NVP 250
#define NN  16000
#define EN  95232
#define LRc 0.01f
#define SQ2 1.41421356237309515f

#define CAP_ES 1024
#define CAP_N1 2048
#define CAP_E0 8192
#define EBLK ((EN + 255) / 256)   // 372
#define NBLK ((NN + 255) / 256)   // 63
#define SK_T 4

// ---------------- GEMM core: 128 thr, BM=32, BN=64, BK=32, acc 4x4 ----------------
// As[kk][mr] pad 36, Bs[kk][nr] pad 68 (both f4-aligned rows).
// Inner loop: 2 x ds_read_b128 per 16 FMA.
template<int VECW>
__device__ __forceinline__ void gemm_core(
    const float* __restrict__ Ain, int Astride,
    const float* __restrict__ W, int Wld, int Woff,
    int M, int mBase, int nBase, int kBeg, int kEnd,
    float (*As)[36], float (*Bs)[68], float acc[4][4]) {
  const int t = threadIdx.x;
  const int tx = t & 15, ty = t >> 4;
  for (int k0 = kBeg; k0 < kEnd; k0 += 32) {
#pragma unroll
    for (int h = 0; h < 2; h++) {
      int q = h*128 + t;
      int mr = q >> 3, k4 = q & 7;
      float4 av = make_float4(0.f,0.f,0.f,0.f);
      int ar = mBase + mr;
      if (ar < M) av = *(const float4*)&Ain[(size_t)ar*Astride + k0 + k4*4];
      As[k4*4+0][mr] = av.x; As[k4*4+1][mr] = av.y;
      As[k4*4+2][mr] = av.z; As[k4*4+3][mr] = av.w;
    }
#pragma unroll
    for (int h = 0; h < 4; h++) {
      int q = h*128 + t;
      int nr = q >> 3, k4 = q & 7;
      const float* wr = W + (size_t)(nBase+nr)*Wld + Woff + k0 + k4*4;
      if (VECW) {
        float4 wv = *(const float4*)wr;
        Bs[k4*4+0][nr] = wv.x; Bs[k4*4+1][nr] = wv.y;
        Bs[k4*4+2][nr] = wv.z; Bs[k4*4+3][nr] = wv.w;
      } else {
        Bs[k4*4+0][nr] = wr[0]; Bs[k4*4+1][nr] = wr[1];
        Bs[k4*4+2][nr] = wr[2]; Bs[k4*4+3][nr] = wr[3];
      }
    }
    __syncthreads();
#pragma unroll
    for (int kk = 0; kk < 32; kk++) {
      float4 a4 = *(const float4*)&As[kk][ty*4];
      float4 b4 = *(const float4*)&Bs[kk][tx*4];
      float aa[4] = {a4.x, a4.y, a4.z, a4.w};
      float bb[4] = {b4.x, b4.y, b4.z, b4.w};
#pragma unroll
      for (int i = 0; i < 4; i++)
#pragma unroll
        for (int j = 0; j < 4; j++) acc[i][j] += aa[i]*bb[j];
    }
    __syncthreads();
  }
}

struct GPP {
  const float* W; const float* Ain; float* pbuf; const int* Mdev;
  int Wld, Woff, K, KC, Mcap, Mfix;
};

// split-K partial writer
template<int VECW>
__global__ __launch_bounds__(128) void gemmP(GPP p) {
  int M = p.Mdev ? *p.Mdev : p.Mfix;
  if (M > p.Mcap) M = p.Mcap;
  const int mBase = blockIdx.x * 32;
  if (mBase >= M) return;
  const int nBase = blockIdx.y * 64;
  const int z = blockIdx.z;
  int kBeg = z * p.KC;
  int kEnd = kBeg + p.KC; if (kEnd > p.K) kEnd = p.K;
  __shared__ float As[32][36];
  __shared__ float Bs[32][68];
  float acc[4][4] = {};
  gemm_core<VECW>(p.Ain, p.K, p.W, p.Wld, p.Woff, M, mBase, nBase, kBeg, kEnd, As, Bs, acc);
  const int tx = threadIdx.x & 15, ty = threadIdx.x >> 4;
#pragma unroll
  for (int i = 0; i < 4; i++) {
    int r = mBase + ty*4 + i;
    *(float4*)&p.pbuf[((size_t)z*p.Mcap + r)*512 + nBase + tx*4] =
      make_float4(acc[i][0],acc[i][1],acc[i][2],acc[i][3]);
  }
}

// P0 edge L1 fused: SK=1, K=512, A=h0c, W=p0ew1; epilogue: ef0c store + atomicAdd agg0c
struct GPF {
  const float* W; const float* Ain; const float* bias;
  const int* Mdev; const int* rmap; const int* dst; const int* posN;
  float* outp; float* atomp; float gain;
};
__global__ __launch_bounds__(128) void gemmF1(GPF p) {
  int M = *p.Mdev; if (M > CAP_E0) M = CAP_E0;
  const int mBase = blockIdx.x * 32;
  if (mBase >= M) return;
  const int nBase = blockIdx.y * 64;
  __shared__ float As[32][36];
  __shared__ float Bs[32][68];
  float acc[4][4] = {};
  gemm_core<1>(p.Ain, 512, p.W, 512, 0, M, mBase, nBase, 0, 512, As, Bs, acc);
  const int tx = threadIdx.x & 15, ty = threadIdx.x >> 4;
  float4 bv = *(const float4*)&p.bias[nBase + tx*4];
  float bb[4] = {bv.x, bv.y, bv.z, bv.w};
#pragma unroll
  for (int i = 0; i < 4; i++) {
    int r = mBase + ty*4 + i;
    if (r >= M) continue;
    float ys[4];
#pragma unroll
    for (int j = 0; j < 4; j++) {
      float y = acc[i][j] * p.gain + bb[j] * LRc;
      ys[j] = (y > 0.f ? y : 0.2f*y) * SQ2;
    }
    *(float4*)&p.outp[(size_t)r*512 + nBase + tx*4] = make_float4(ys[0],ys[1],ys[2],ys[3]);
    int tr = p.posN[p.dst[p.rmap[r]]];
#pragma unroll
    for (int j = 0; j < 4; j++)
      atomicAdd(&p.atomp[(size_t)tr*512 + nBase + tx*4 + j], ys[j]);
  }
}

// fused 3-table GEMM: Ts/Td/T0, grid (2, 24, SK_T)
struct TABP { const float* zn; const float* We; const float* Wn;
              float* pbTs; float* pbTd; float* pbT0; };
__global__ __launch_bounds__(128) void tab_k(TABP q) {
  int wsel = blockIdx.y >> 3;
  int nBase = (blockIdx.y & 7) * 64;
  const float* W = (wsel == 2) ? q.Wn : q.We;
  int Wld = (wsel == 2) ? 1030 : 1034;
  int Woff = (wsel == 1) ? 515 : 0;
  float* pb = (wsel == 0) ? q.pbTs : (wsel == 1) ? q.pbTd : q.pbT0;
  int z = blockIdx.z;
  __shared__ float As[32][36];
  __shared__ float Bs[32][68];
  float acc[4][4] = {};
  gemm_core<0>(q.zn, 512, W, Wld, Woff, 64, blockIdx.x*32, nBase, z*128, z*128+128, As, Bs, acc);
  const int tx = threadIdx.x & 15, ty = threadIdx.x >> 4;
#pragma unroll
  for (int i = 0; i < 4; i++) {
    int r = blockIdx.x*32 + ty*4 + i;
    *(float4*)&pb[((size_t)z*64 + r)*512 + nBase + tx*4] =
      make_float4(acc[i][0],acc[i][1],acc[i][2],acc[i][3]);
  }
}

struct EPP {
  const float* pbuf; const float* bias; const float* T0p; const float* la;
  const float* cnt; const float* w0n;
  const int* rmap; const int* dst; const int* posN; const int* Mdev;
  float* outp; float* atomp;
  int SK, Mcap, Mfix; float gain;
};

// EPI 0: store. EPI 2: atomicAdd agg1c[dst/250]. EPI 7: +T0 +la*w0n, store. EPI 8: 14x tile to out.
template<int EPI>
__global__ __launch_bounds__(256) void epi_k(EPP e) {
  int M = e.Mdev ? *e.Mdev : e.Mfix;
  if (M > e.Mcap) M = e.Mcap;
  int i = blockIdx.x*256 + threadIdx.x;
  if (i >= M*128) return;
  int m = i >> 7, n4 = (i & 127) * 4;
  float ys[4] = {0.f, 0.f, 0.f, 0.f};
  for (int z = 0; z < e.SK; z++) {
    float4 v = *(const float4*)&e.pbuf[((size_t)z*e.Mcap + m)*512 + n4];
    ys[0] += v.x; ys[1] += v.y; ys[2] += v.z; ys[3] += v.w;
  }
  if (EPI == 7) {
    int nd = e.rmap[m];
    int rr = nd & 63;
#pragma unroll
    for (int z = 0; z < SK_T; z++) {
      float4 v = *(const float4*)&e.T0p[((size_t)z*64 + rr)*512 + n4];
      ys[0] += v.x; ys[1] += v.y; ys[2] += v.z; ys[3] += v.w;
    }
    float l0 = e.la[nd*3], l1 = e.la[nd*3+1], l2 = e.la[nd*3+2];
    bool has = e.cnt[nd] > 0.f;
#pragma unroll
    for (int j = 0; j < 4; j++) {
      int n = n4 + j;
      float corr = l0*e.w0n[0*512+n] + l1*e.w0n[1*512+n] + l2*e.w0n[2*512+n];
      if (has) corr += l0*e.w0n[3*512+n] + l1*e.w0n[4*512+n] + l2*e.w0n[5*512+n];
      ys[j] += corr;
    }
  }
#pragma unroll
  for (int j = 0; j < 4; j++) {
    float y = ys[j] * e.gain + e.bias[n4+j] * LRc;
    ys[j] = (y > 0.f ? y : 0.2f*y) * SQ2;
  }
  float4 ov = make_float4(ys[0], ys[1], ys[2], ys[3]);
  if (EPI == 0 || EPI == 7) {
    *(float4*)&e.outp[(size_t)m*512 + n4] = ov;
  } else if (EPI == 2) {
    int tr = e.dst[e.rmap[m]] / NVP;
#pragma unroll
    for (int j = 0; j < 4; j++) atomicAdd(&e.atomp[(size_t)tr*512 + n4 + j], ys[j]);
  } else { // 8
#pragma unroll
    for (int w = 0; w < 14; w++)
      *(float4*)&e.outp[((size_t)(m*14 + w))*512 + n4] = ov;
  }
}

// fused init: blocks 0-63 rms, 64-126 need-flags, 127-128 small-W transposes
__global__ __launch_bounds__(256) void init_k(const float* z, float* zn, int* need,
                                              const float* W0, const float* Wn,
                                              float* w0s, float* w0n) {
  int b = blockIdx.x, t = threadIdx.x;
  if (b < 64) {
    float s = 0.f;
    for (int j = t; j < 512; j += 256) { float v = z[b*512+j]; s += v*v; }
    for (int o = 32; o > 0; o >>= 1) s += __shfl_down(s, o);
    __shared__ float red[5];
    if ((t & 63) == 0) red[t >> 6] = s;
    __syncthreads();
    if (t == 0) {
      float tot = red[0]+red[1]+red[2]+red[3];
      red[4] = 1.0f / sqrtf(tot * (1.0f/512.0f) + 1e-8f);
    }
    __syncthreads();
    float r = red[4];
    for (int j = t; j < 512; j += 256) zn[b*512+j] = z[b*512+j] * r;
  } else if (b < 127) {
    int n = (b-64)*256 + t;
    if (n < NN) need[n] = ((n % NVP) == 0) ? 1 : 0;
  } else {
    int c = (b-127)*256 + t;
    const float* row = W0 + (size_t)c*1034;
    w0s[0*512+c] = row[512];  w0s[1*512+c] = row[513];  w0s[2*512+c] = row[514];
    w0s[3*512+c] = row[1027]; w0s[4*512+c] = row[1028]; w0s[5*512+c] = row[1029];
    w0s[6*512+c] = row[1030]; w0s[7*512+c] = row[1031]; w0s[8*512+c] = row[1032];
    w0s[9*512+c] = row[1033];
    const float* rn = Wn + (size_t)c*1030;
#pragma unroll
    for (int j = 0; j < 6; j++) w0n[j*512+c] = rn[512+j];
  }
}

// ---- deterministic compaction ----
__device__ __forceinline__ int blockCount(int pred, int* ws4) {
  unsigned long long m = __ballot(pred);
  int lane = threadIdx.x & 63, w = threadIdx.x >> 6;
  if (lane == 0) ws4[w] = __popcll(m);
  __syncthreads();
  return ws4[0] + ws4[1] + ws4[2] + ws4[3];
}
__device__ __forceinline__ int blockRank(int pred, int* ws4) {
  unsigned long long m = __ballot(pred);
  int lane = threadIdx.x & 63, w = threadIdx.x >> 6;
  if (lane == 0) ws4[w] = __popcll(m);
  __syncthreads();
  int off = 0;
  for (int i = 0; i < w; i++) off += ws4[i];
  return off + __popcll(m & ((1ull << lane) - 1ull));
}

__global__ __launch_bounds__(256) void cntES_k(const int* dst, float* cnt, int* bcnt) {
  __shared__ int ws4[4];
  int e = blockIdx.x*256 + threadIdx.x;
  int pred = 0;
  if (e < EN) {
    int d = dst[e];
    atomicAdd(&cnt[d], 1.0f);   // integer-valued: exact, order-free
    pred = (d % NVP) == 0;
  }
  int c = blockCount(pred, ws4);
  if (threadIdx.x == 0) bcnt[blockIdx.x] = c;
}
__global__ __launch_bounds__(256) void emitES_k(const int* src, const int* dst,
                                                const int* boff, int* listES, int* need) {
  __shared__ int ws4[4];
  int e = blockIdx.x*256 + threadIdx.x;
  int pred = (e < EN) && (dst[e] % NVP == 0);
  int rank = blockRank(pred, ws4);
  if (pred) {
    int pos = boff[blockIdx.x] + rank;
    if (pos < CAP_ES) listES[pos] = e;
    need[src[e]] = 1;
  }
}
__global__ __launch_bounds__(256) void cntE0N1_k(const int* dst, const int* need,
                                                 int* bcntE, int* bcntN) {
  __shared__ int ws4[4];
  int b = blockIdx.x;
  if (b < EBLK) {
    int e = b*256 + threadIdx.x;
    int pred = (e < EN) && need[dst[e]];
    int c = blockCount(pred, ws4);
    if (threadIdx.x == 0) bcntE[b] = c;
  } else {
    int n = (b-EBLK)*256 + threadIdx.x;
    int pred = (n < NN) && need[n];
    int c = blockCount(pred, ws4);
    if (threadIdx.x == 0) bcntN[b-EBLK] = c;
  }
}
__global__ __launch_bounds__(256) void emitE0N1_k(const int* dst, const int* need,
                                                  const int* boffE, int* listE0, int* posOf,
                                                  const int* boffN, int* listN1, int* posN) {
  __shared__ int ws4[4];
  int b = blockIdx.x;
  if (b < EBLK) {
    int e = b*256 + threadIdx.x;
    int pred = (e < EN) && need[dst[e]];
    int rank = blockRank(pred, ws4);
    if (pred) {
      int pos = boffE[b] + rank;
      if (pos < CAP_E0) { listE0[pos] = e; posOf[e] = pos; }
    }
  } else {
    int n = (b-EBLK)*256 + threadIdx.x;
    int pred = (n < NN) && need[n];
    int rank = blockRank(pred, ws4);
    if (pred) {
      int pos = boffN[b-EBLK] + rank;
      if (pos < CAP_N1) { listN1[pos] = n; posN[n] = pos; }
    }
  }
}

__global__ __launch_bounds__(512) void scan_k(const int* bcnt, int n, int* boff, int* tot) {
  __shared__ int s[512];
  int t = threadIdx.x;
  int orig = (t < n) ? bcnt[t] : 0;
  s[t] = orig;
  __syncthreads();
  for (int o = 1; o < 512; o <<= 1) {
    int v = (t >= o) ? s[t-o] : 0;
    __syncthreads();
    s[t] += v;
    __syncthreads();
  }
  if (t < n) boff[t] = s[t] - orig;
  if (t == n-1) *tot = s[t];
}
__global__ __launch_bounds__(512) void scan2_k(const int* bcntA, int nA, int* boffA, int* totA,
                                               const int* bcntB, int nB, int* boffB, int* totB) {
  const int* bcnt; int n; int* boff; int* tot;
  if (blockIdx.x == 0) { bcnt = bcntA; n = nA; boff = boffA; tot = totA; }
  else                 { bcnt = bcntB; n = nB; boff = boffB; tot = totB; }
  __shared__ int s[512];
  int t = threadIdx.x;
  int orig = (t < n) ? bcnt[t] : 0;
  s[t] = orig;
  __syncthreads();
  for (int o = 1; o < 512; o <<= 1) {
    int v = (t >= o) ? s[t-o] : 0;
    __syncthreads();
    s[t] += v;
    __syncthreads();
  }
  if (t < n) boff[t] = s[t] - orig;
  if (t == n-1) *tot = s[t];
}

__global__ __launch_bounds__(256) void rows_k(const int* nESp, const int* listES,
                                              const int* src, const int* dst,
                                              const int* posN, const int* posOf,
                                              int* rowS, int* rowD, int* rowE) {
  int n = *nESp; if (n > CAP_ES) n = CAP_ES;
  int i = blockIdx.x*256 + threadIdx.x;
  if (i >= n) return;
  int e = listES[i];
  rowS[i] = posN[src[e]];
  rowD[i] = posN[dst[e]];
  rowE[i] = posOf[e];
}

// P0 edge L0 via Ts/Td partial tables, float4
__global__ __launch_bounds__(128) void edge0_k(const int* nE0p, const int* listE0,
                                               const int* src, const int* dst,
                                               const float* pbTs, const float* pbTd,
                                               const float* la, const float* w0s,
                                               const float* b0, float* h0c) {
  int i = blockIdx.x;
  int n0 = *nE0p; if (n0 > CAP_E0) n0 = CAP_E0;
  if (i >= n0) return;
  int tid = threadIdx.x;
  int e = listE0[i];
  int s = src[e], d = dst[e];
  float a0 = la[s*3], a1 = la[s*3+1], a2 = la[s*3+2];
  float c0 = la[d*3], c1 = la[d*3+1], c2 = la[d*3+2];
  float r0 = c0-a0, r1 = c1-a1, r2 = c2-a2;
  float dn = sqrtf(r0*r0 + r1*r1 + r2*r2);
  const float g = LRc / 32.1558704423f; // sqrt(1034)
  int sr = s & 63, dr = d & 63;
  int c4 = tid*4;
  float ys[4] = {0.f,0.f,0.f,0.f};
#pragma unroll
  for (int z = 0; z < SK_T; z++) {
    float4 vs = *(const float4*)&pbTs[((size_t)z*64 + sr)*512 + c4];
    float4 vd = *(const float4*)&pbTd[((size_t)z*64 + dr)*512 + c4];
    ys[0] += vs.x + vd.x; ys[1] += vs.y + vd.y;
    ys[2] += vs.z + vd.z; ys[3] += vs.w + vd.w;
  }
  float cf[10] = {a0,a1,a2,c0,c1,c2,r0,r1,r2,dn};
#pragma unroll
  for (int j = 0; j < 10; j++) {
    float4 wv = *(const float4*)&w0s[j*512 + c4];
    ys[0] += cf[j]*wv.x; ys[1] += cf[j]*wv.y; ys[2] += cf[j]*wv.z; ys[3] += cf[j]*wv.w;
  }
  float4 bv = *(const float4*)&b0[c4];
  float bb[4] = {bv.x, bv.y, bv.z, bv.w};
#pragma unroll
  for (int j = 0; j < 4; j++) {
    float y = ys[j]*g + bb[j]*LRc;
    ys[j] = (y > 0.f ? y : 0.2f*y) * SQ2;
  }
  *(float4*)&h0c[(size_t)i*512 + c4] = make_float4(ys[0],ys[1],ys[2],ys[3]);
}

__global__ __launch_bounds__(256) void scaleAgg0_k(const int* nN1p, const int* listN1,
                                                   const float* cnt, float* agg0c) {
  int n1 = *nN1p; if (n1 > CAP_N1) n1 = CAP_N1;
  int i = blockIdx.x*256 + threadIdx.x;
  if (i >= n1*128) return;
  int m = i >> 7;
  float rinv = 1.0f / fmaxf(cnt[listN1[m]], 1.0f);
  float4* pp = (float4*)&agg0c[(size_t)m*512 + (i & 127)*4];
  float4 v = *pp;
  v.x *= rinv; v.y *= rinv; v.z *= rinv; v.w *= rinv;
  *pp = v;
}

__global__ __launch_bounds__(256) void buildAes_k(const int* nESp, const int* rowS,
                                                  const int* rowD, const int* rowE,
                                                  const float* x1c, const float* ef0c,
                                                  float* Aes) {
  int i = blockIdx.x;
  int n = *nESp; if (n > CAP_ES) n = CAP_ES;
  if (i >= n) return;
  int rs = rowS[i], rd = rowD[i], re = rowE[i];
  for (int q = threadIdx.x; q < 384; q += 256) {
    int seg = q >> 7, w = (q & 127)*4;
    const float* sp = (seg == 0) ? &x1c[(size_t)rs*512 + w]
                    : (seg == 1) ? &x1c[(size_t)rd*512 + w]
                                 : &ef0c[(size_t)re*512 + w];
    *(float4*)&Aes[(size_t)i*1536 + q*4] = *(const float4*)sp;
  }
}

__global__ __launch_bounds__(256) void buildA64_k(const int* posN, const float* x1c,
                                                  const float* agg1c, const float* cnt,
                                                  float* A64) {
  int m = blockIdx.x;
  int q = threadIdx.x;
  if (q < 128) {
    *(float4*)&A64[(size_t)m*1024 + q*4] =
      *(const float4*)&x1c[(size_t)posN[m*NVP]*512 + q*4];
  } else {
    float rinv = 1.0f / fmaxf(cnt[m*NVP], 1.0f);
    int w = (q - 128)*4;
    float4 v = *(const float4*)&agg1c[(size_t)m*512 + w];
    v.x *= rinv; v.y *= rinv; v.z *= rinv; v.w *= rinv;
    *(float4*)&A64[(size_t)m*1024 + 512 + w] = v;
  }
}

extern "C" void kernel_launch(void* const* d_in, const int* in_sizes, int n_in,
                              void* d_out, int out_size, void* d_ws, size_t ws_size,
                              hipStream_t stream) {
  const float* z     = (const float*)d_in[0];
  const float* la    = (const float*)d_in[1];
  const int*   ei    = (const int*)  d_in[2];
  const float* p0ew0 = (const float*)d_in[3];
  const float* p0eb0 = (const float*)d_in[4];
  const float* p0ew1 = (const float*)d_in[5];
  const float* p0eb1 = (const float*)d_in[6];
  const float* p0nw0 = (const float*)d_in[7];
  const float* p0nb0 = (const float*)d_in[8];
  const float* p0nw1 = (const float*)d_in[9];
  const float* p0nb1 = (const float*)d_in[10];
  const float* p1ew0 = (const float*)d_in[11];
  const float* p1eb0 = (const float*)d_in[12];
  const float* p1ew1 = (const float*)d_in[13];
  const float* p1eb1 = (const float*)d_in[14];
  const float* p1nw0 = (const float*)d_in[15];
  const float* p1nb0 = (const float*)d_in[16];
  const float* p1nw1 = (const float*)d_in[17];
  const float* p1nb1 = (const float*)d_in[18];
  const int* src = ei;
  const int* dst = ei + EN;

  char* ws = (char*)d_ws;
  size_t off = 0;
  auto al = [&](size_t bytes) -> void* {
    void* r = (void*)(ws + off);
    off += (bytes + 255) & ~(size_t)255;
    return r;
  };
  // ---- zeroed region ----
  int*   tot    = (int*)  al(3*4);
  float* cnt    = (float*)al(NN*4);
  int*   need   = (int*)  al(NN*4);
  int*   posN   = (int*)  al(NN*4);
  int*   posOf  = (int*)  al((size_t)EN*4);
  int*   bcntE  = (int*)  al(EBLK*4);
  int*   boffE  = (int*)  al(EBLK*4);
  int*   bcntN  = (int*)  al(NBLK*4);
  int*   boffN  = (int*)  al(NBLK*4);
  int*   listES = (int*)  al(CAP_ES*4);
  int*   listN1 = (int*)  al(CAP_N1*4);
  int*   listE0 = (int*)  al(CAP_E0*4);
  float* agg0c  = (float*)al((size_t)CAP_N1*512*4);
  float* agg1c  = (float*)al(64*512*4);
  size_t zEnd = off;
  // ---- written-before-read region ----
  int*   rowS   = (int*)  al(CAP_ES*4);
  int*   rowD   = (int*)  al(CAP_ES*4);
  int*   rowE   = (int*)  al(CAP_ES*4);
  float* zn     = (float*)al(64*512*4);
  float* w0s    = (float*)al(10*512*4);
  float* w0n    = (float*)al(6*512*4);
  float* pbTs   = (float*)al((size_t)SK_T*64*512*4);
  float* pbTd   = (float*)al((size_t)SK_T*64*512*4);
  float* pbT0   = (float*)al((size_t)SK_T*64*512*4);
  float* h0c    = (float*)al((size_t)CAP_E0*512*4);
  float* ef0c   = (float*)al((size_t)CAP_E0*512*4);
  float* hn1    = (float*)al((size_t)CAP_N1*512*4);
  float* x1c    = (float*)al((size_t)CAP_N1*512*4);
  float* Aes    = (float*)al((size_t)CAP_ES*1536*4);
  float* hs     = (float*)al((size_t)CAP_ES*512*4);
  float* A64    = (float*)al(64*1024*4);
  float* hn64   = (float*)al(64*512*4);
  float* pbuf   = (float*)al((size_t)CAP_E0*512*2*4);

  hipMemsetAsync(ws, 0, zEnd, stream);

  init_k<<<129, 256, 0, stream>>>(z, zn, need, p0ew0, p0nw0, w0s, w0n);

  cntES_k<<<EBLK, 256, 0, stream>>>(dst, cnt, bcntE);
  scan_k<<<1, 512, 0, stream>>>(bcntE, EBLK, boffE, tot+0);
  emitES_k<<<EBLK, 256, 0, stream>>>(src, dst, boffE, listES, need);

  cntE0N1_k<<<EBLK+NBLK, 256, 0, stream>>>(dst, need, bcntE, bcntN);
  scan2_k<<<2, 512, 0, stream>>>(bcntE, EBLK, boffE, tot+1, bcntN, NBLK, boffN, tot+2);
  emitE0N1_k<<<EBLK+NBLK, 256, 0, stream>>>(dst, need, boffE, listE0, posOf,
                                            boffN, listN1, posN);

  rows_k<<<CAP_ES/256, 256, 0, stream>>>(tot+0, listES, src, dst, posN, posOf,
                                         rowS, rowD, rowE);

  // Ts/Td/T0 tables in one launch
  {
    TABP q{zn, p0ew0, p0nw0, pbTs, pbTd, pbT0};
    tab_k<<<dim3(2, 24, SK_T), 128, 0, stream>>>(q);
  }

  edge0_k<<<CAP_E0, 128, 0, stream>>>(tot+1, listE0, src, dst, pbTs, pbTd, la, w0s,
                                      p0eb0, h0c);

  // P0 edge L1: fused SK=1 GEMM -> ef0c + atomic agg0c
  {
    GPF p{}; p.W = p0ew1; p.Ain = h0c; p.bias = p0eb1; p.gain = LRc/sqrtf(512.f);
    p.Mdev = tot+1; p.rmap = listE0; p.dst = dst; p.posN = posN;
    p.outp = ef0c; p.atomp = agg0c;
    gemmF1<<<dim3(CAP_E0/32, 8), 128, 0, stream>>>(p);
  }
  scaleAgg0_k<<<(CAP_N1*128)/256, 256, 0, stream>>>(tot+2, listN1, cnt, agg0c);

  // P0 node L0: dense over scaled agg0c (W cols 518..1029) + epi7
  {
    GPP p{}; p.W = p0nw0; p.Wld = 1030; p.Woff = 518; p.K = 512; p.KC = 128;
    p.Mcap = CAP_N1; p.Mdev = tot+2; p.Ain = agg0c; p.pbuf = pbuf;
    gemmP<0><<<dim3(CAP_N1/32, 8, 4), 128, 0, stream>>>(p);
    EPP e{}; e.pbuf = pbuf; e.SK = 4; e.Mcap = CAP_N1; e.Mdev = tot+2;
    e.bias = p0nb0; e.gain = LRc/sqrtf(1030.f);
    e.T0p = pbT0; e.rmap = listN1; e.la = la; e.cnt = cnt; e.w0n = w0n; e.outp = hn1;
    epi_k<7><<<(CAP_N1*128)/256, 256, 0, stream>>>(e);
  }
  // P0 node L1 -> x1c
  {
    GPP p{}; p.W = p0nw1; p.Wld = 512; p.Woff = 0; p.K = 512; p.KC = 128;
    p.Mcap = CAP_N1; p.Mdev = tot+2; p.Ain = hn1; p.pbuf = pbuf;
    gemmP<1><<<dim3(CAP_N1/32, 8, 4), 128, 0, stream>>>(p);
    EPP e{}; e.pbuf = pbuf; e.SK = 4; e.Mcap = CAP_N1; e.Mdev = tot+2;
    e.bias = p0nb1; e.gain = LRc/sqrtf(512.f); e.outp = x1c;
    epi_k<0><<<(CAP_N1*128)/256, 256, 0, stream>>>(e);
  }
  buildAes_k<<<CAP_ES, 256, 0, stream>>>(tot+0, rowS, rowD, rowE, x1c, ef0c, Aes);

  // P1 edge L0: dense K=1536, SK=6 -> hs
  {
    GPP p{}; p.W = p1ew0; p.Wld = 1536; p.Woff = 0; p.K = 1536; p.KC = 256;
    p.Mcap = CAP_ES; p.Mdev = tot+0; p.Ain = Aes; p.pbuf = pbuf;
    gemmP<1><<<dim3(CAP_ES/32, 8, 6), 128, 0, stream>>>(p);
    EPP e{}; e.pbuf = pbuf; e.SK = 6; e.Mcap = CAP_ES; e.Mdev = tot+0;
    e.bias = p1eb0; e.gain = LRc/sqrtf(1536.f); e.outp = hs;
    epi_k<0><<<(CAP_ES*128)/256, 256, 0, stream>>>(e);
  }
  // P1 edge L1: dense K=512, SK=4 -> atomic agg1c
  {
    GPP p{}; p.W = p1ew1; p.Wld = 512; p.Woff = 0; p.K = 512; p.KC = 128;
    p.Mcap = CAP_ES; p.Mdev = tot+0; p.Ain = hs; p.pbuf = pbuf;
    gemmP<1><<<dim3(CAP_ES/32, 8, 4), 128, 0, stream>>>(p);
    EPP e{}; e.pbuf = pbuf; e.SK = 4; e.Mcap = CAP_ES; e.Mdev = tot+0;
    e.bias = p1eb1; e.gain = LRc/sqrtf(512.f);
    e.rmap = listES; e.dst = dst; e.atomp = agg1c;
    epi_k<2><<<(CAP_ES*128)/256, 256, 0, stream>>>(e);
  }
  buildA64_k<<<64, 256, 0, stream>>>(posN, x1c, agg1c, cnt, A64);

  // P1 node L0: dense K=1024, SK=8 -> hn64
  {
    GPP p{}; p.W = p1nw0; p.Wld = 1024; p.Woff = 0; p.K = 1024; p.KC = 128;
    p.Mcap = 64; p.Mfix = 64; p.Mdev = nullptr; p.Ain = A64; p.pbuf = pbuf;
    gemmP<1><<<dim3(2, 8, 8), 128, 0, stream>>>(p);
    EPP e{}; e.pbuf = pbuf; e.SK = 8; e.Mcap = 64; e.Mfix = 64;
    e.bias = p1nb0; e.gain = LRc/sqrtf(1024.f); e.outp = hn64;
    epi_k<0><<<(64*128)/256, 256, 0, stream>>>(e);
  }
  // P1 node L1: dense K=512, SK=4 -> d_out (14x tiled)
  {
    GPP p{}; p.W = p1nw1; p.Wld = 512; p.Woff = 0; p.K = 512; p.KC = 128;
    p.Mcap = 64; p.Mfix = 64; p.Mdev = nullptr; p.Ain = hn64; p.pbuf = pbuf;
    gemmP<1><<<dim3(2, 8, 4), 128, 0, stream>>>(p);
    EPP e{}; e.pbuf = pbuf; e.SK = 4; e.Mcap = 64; e.Mfix = 64;
    e.bias = p1nb1; e.gain = LRc/sqrtf(512.f); e.outp = (float*)d_out;
    epi_k<8><<<(64*128)/256, 256, 0, stream>>>(e);
  }
}

// Round 7
// 216.956 us; speedup vs baseline: 85.7690x; 1.2000x over previous
//
#include <hip/hip_runtime.h>
#include <hip/hip_bf16.h>
#include <cmath>

#define NVP 250
#define NN  16000
#define EN  95232
#define LRc 0.01f
#define SQ2 1.41421356237309515f

#define CAP_ES 1024
#define CAP_N1 1024
#define CAP_E0 4096
#define EBLK ((EN + 255) / 256)   // 372
#define NBLK ((NN + 255) / 256)   // 63
#define SK_T 4

// ---------------- pipelined GEMM inner loop ----------------
// 128 thr, BM=32, BN=64, BK=32, acc 4x4. As[kk][mr] pad36, Bs[kk][nr] pad68.
// Register-prefetch: next tile's global loads issued right after the store
// barrier, overlapping the 32-FMA compute phase.
template<int VECW, int GATHER>
__device__ __forceinline__ void gemm_loop(
    const float* const a0s[3], const float* const a1s[3], float s0, float s1,
    const float* w0, const float* w1, const float* w2, const float* w3,
    int kBeg, int kEnd,
    float (*As)[36], float (*Bs)[68], float acc[4][4]) {
  const int t = threadIdx.x;
  const int k4 = (t & 7) * 4;
  const int mr = t >> 3;
  const int tx = t & 15, ty = t >> 4;
  float4 ra0, ra1, rw0, rw1, rw2, rw3;
  auto lA = [&](int k0) {
    int ka = k0 + k4;
    if (GATHER) {
      const float* b0 = (ka < 512) ? a0s[0] : (ka < 1024) ? a0s[1] : a0s[2];
      const float* b1 = (ka < 512) ? a1s[0] : (ka < 1024) ? a1s[1] : a1s[2];
      ra0 = *(const float4*)(b0 + ka);
      ra1 = *(const float4*)(b1 + ka);
    } else {
      ra0 = *(const float4*)(a0s[0] + ka);
      ra1 = *(const float4*)(a1s[0] + ka);
    }
  };
  auto lW = [&](int k0) {
    if (VECW) {
      rw0 = *(const float4*)(w0 + k0); rw1 = *(const float4*)(w1 + k0);
      rw2 = *(const float4*)(w2 + k0); rw3 = *(const float4*)(w3 + k0);
    } else {
      rw0 = make_float4(w0[k0], w0[k0+1], w0[k0+2], w0[k0+3]);
      rw1 = make_float4(w1[k0], w1[k0+1], w1[k0+2], w1[k0+3]);
      rw2 = make_float4(w2[k0], w2[k0+1], w2[k0+2], w2[k0+3]);
      rw3 = make_float4(w3[k0], w3[k0+1], w3[k0+2], w3[k0+3]);
    }
  };
  lA(kBeg); lW(kBeg);
  for (int k0 = kBeg; k0 < kEnd; k0 += 32) {
    if (k0 > kBeg) __syncthreads();
    As[k4+0][mr] = ra0.x*s0; As[k4+1][mr] = ra0.y*s0;
    As[k4+2][mr] = ra0.z*s0; As[k4+3][mr] = ra0.w*s0;
    As[k4+0][mr+16] = ra1.x*s1; As[k4+1][mr+16] = ra1.y*s1;
    As[k4+2][mr+16] = ra1.z*s1; As[k4+3][mr+16] = ra1.w*s1;
    Bs[k4+0][mr]    = rw0.x; Bs[k4+1][mr]    = rw0.y; Bs[k4+2][mr]    = rw0.z; Bs[k4+3][mr]    = rw0.w;
    Bs[k4+0][mr+16] = rw1.x; Bs[k4+1][mr+16] = rw1.y; Bs[k4+2][mr+16] = rw1.z; Bs[k4+3][mr+16] = rw1.w;
    Bs[k4+0][mr+32] = rw2.x; Bs[k4+1][mr+32] = rw2.y; Bs[k4+2][mr+32] = rw2.z; Bs[k4+3][mr+32] = rw2.w;
    Bs[k4+0][mr+48] = rw3.x; Bs[k4+1][mr+48] = rw3.y; Bs[k4+2][mr+48] = rw3.z; Bs[k4+3][mr+48] = rw3.w;
    __syncthreads();
    if (k0 + 32 < kEnd) { lA(k0 + 32); lW(k0 + 32); }
#pragma unroll
    for (int kk = 0; kk < 32; kk++) {
      float4 a4 = *(const float4*)&As[kk][ty*4];
      float4 b4 = *(const float4*)&Bs[kk][tx*4];
      float aa[4] = {a4.x, a4.y, a4.z, a4.w};
      float bb[4] = {b4.x, b4.y, b4.z, b4.w};
#pragma unroll
      for (int i = 0; i < 4; i++)
#pragma unroll
        for (int j = 0; j < 4; j++) acc[i][j] += aa[i]*bb[j];
    }
  }
}

struct GPP {
  const float* W; const float* Ain; float* pbuf; const int* Mdev;
  const float* cnt; const int* listN1;   // SCALED only
  int Wld, Woff, Astride, K, KC, Mcap, Mfix;
};

// split-K partial writer; SCALED: A row r scaled by 1/max(cnt[listN1[r]],1)
template<int VECW, int SCALED>
__global__ __launch_bounds__(128) void gemmP(GPP p) {
  int M = p.Mdev ? *p.Mdev : p.Mfix;
  if (M > p.Mcap) M = p.Mcap;
  const int mBase = blockIdx.x * 32;
  if (mBase >= M) return;
  const int nBase = blockIdx.y * 64;
  const int z = blockIdx.z;
  int kBeg = z * p.KC;
  int kEnd = kBeg + p.KC; if (kEnd > p.K) kEnd = p.K;
  __shared__ float As[32][36];
  __shared__ float Bs[32][68];
  const int t = threadIdx.x;
  const float* a0s[3]; const float* a1s[3];
  a0s[0] = p.Ain + (size_t)(mBase + (t>>3)) * p.Astride;
  a1s[0] = a0s[0] + (size_t)16 * p.Astride;
  float s0 = 1.f, s1 = 1.f;
  if (SCALED) {
    s0 = 1.0f / fmaxf(p.cnt[p.listN1[mBase + (t>>3)]], 1.0f);
    s1 = 1.0f / fmaxf(p.cnt[p.listN1[mBase + 16 + (t>>3)]], 1.0f);
  }
  const int kofs = (t & 7)*4 + p.Woff;
  const float* w0 = p.W + (size_t)(nBase + (t>>3)) * p.Wld + kofs;
  const float* w1 = w0 + (size_t)16 * p.Wld;
  const float* w2 = w0 + (size_t)32 * p.Wld;
  const float* w3 = w0 + (size_t)48 * p.Wld;
  float acc[4][4] = {};
  gemm_loop<VECW, 0>(a0s, a1s, s0, s1, w0, w1, w2, w3, kBeg, kEnd, As, Bs, acc);
  const int tx = t & 15, ty = t >> 4;
#pragma unroll
  for (int i = 0; i < 4; i++) {
    int r = mBase + ty*4 + i;
    *(float4*)&p.pbuf[((size_t)z*p.Mcap + r)*512 + nBase + tx*4] =
      make_float4(acc[i][0],acc[i][1],acc[i][2],acc[i][3]);
  }
}

// P1 edge L0: gather A = [x1c[posN[src]] | x1c[posN[dst]] | ef0c[posOf]] inside GEMM
struct GGP {
  const float* W; const float* x1c; const float* ef0c;
  const int* listES; const int* src; const int* dst; const int* posN; const int* posOf;
  const int* Mdev; float* pbuf; int KC;
};
__global__ __launch_bounds__(128) void gemmG(GGP p) {
  int M = *p.Mdev; if (M > CAP_ES) M = CAP_ES;
  const int mBase = blockIdx.x * 32;
  if (mBase >= M) return;
  const int nBase = blockIdx.y * 64;
  const int z = blockIdx.z;
  int kBeg = z * p.KC, kEnd = kBeg + p.KC;
  __shared__ float As[32][36];
  __shared__ float Bs[32][68];
  const int t = threadIdx.x;
  int r0 = mBase + (t>>3), r1 = r0 + 16;
  int e0 = p.listES[r0], e1 = p.listES[r1];
  const float* a0s[3] = {
    p.x1c  + (size_t)p.posN[p.src[e0]]*512,
    p.x1c  + (size_t)p.posN[p.dst[e0]]*512 - 512,
    p.ef0c + (size_t)p.posOf[e0]*512 - 1024 };
  const float* a1s[3] = {
    p.x1c  + (size_t)p.posN[p.src[e1]]*512,
    p.x1c  + (size_t)p.posN[p.dst[e1]]*512 - 512,
    p.ef0c + (size_t)p.posOf[e1]*512 - 1024 };
  const int kofs = (t & 7)*4;
  const float* w0 = p.W + (size_t)(nBase + (t>>3)) * 1536 + kofs;
  const float* w1 = w0 + (size_t)16 * 1536;
  const float* w2 = w0 + (size_t)32 * 1536;
  const float* w3 = w0 + (size_t)48 * 1536;
  float acc[4][4] = {};
  gemm_loop<1, 1>(a0s, a1s, 1.f, 1.f, w0, w1, w2, w3, kBeg, kEnd, As, Bs, acc);
  const int tx = t & 15, ty = t >> 4;
#pragma unroll
  for (int i = 0; i < 4; i++) {
    int r = mBase + ty*4 + i;
    *(float4*)&p.pbuf[((size_t)z*CAP_ES + r)*512 + nBase + tx*4] =
      make_float4(acc[i][0],acc[i][1],acc[i][2],acc[i][3]);
  }
}

// fused 3-table GEMM: Ts/Td/T0, grid (2, 24, SK_T)
struct TABP { const float* zn; const float* We; const float* Wn;
              float* pbTs; float* pbTd; float* pbT0; };
__global__ __launch_bounds__(128) void tab_k(TABP q) {
  int wsel = blockIdx.y >> 3;
  int nBase = (blockIdx.y & 7) * 64;
  const float* W = (wsel == 2) ? q.Wn : q.We;
  int Wld = (wsel == 2) ? 1030 : 1034;
  int Woff = (wsel == 1) ? 515 : 0;
  float* pb = (wsel == 0) ? q.pbTs : (wsel == 1) ? q.pbTd : q.pbT0;
  int z = blockIdx.z;
  __shared__ float As[32][36];
  __shared__ float Bs[32][68];
  const int t = threadIdx.x;
  const int mBase = blockIdx.x * 32;
  const float* a0s[3]; const float* a1s[3];
  a0s[0] = q.zn + (size_t)(mBase + (t>>3)) * 512;
  a1s[0] = a0s[0] + 16*512;
  const int kofs = (t & 7)*4 + Woff;
  const float* w0 = W + (size_t)(nBase + (t>>3)) * Wld + kofs;
  const float* w1 = w0 + (size_t)16 * Wld;
  const float* w2 = w0 + (size_t)32 * Wld;
  const float* w3 = w0 + (size_t)48 * Wld;
  float acc[4][4] = {};
  gemm_loop<0, 0>(a0s, a1s, 1.f, 1.f, w0, w1, w2, w3, z*128, z*128+128, As, Bs, acc);
  const int tx = t & 15, ty = t >> 4;
#pragma unroll
  for (int i = 0; i < 4; i++) {
    int r = mBase + ty*4 + i;
    *(float4*)&pb[((size_t)z*64 + r)*512 + nBase + tx*4] =
      make_float4(acc[i][0],acc[i][1],acc[i][2],acc[i][3]);
  }
}

struct EPP {
  const float* pbuf; const float* bias; const float* T0p; const float* la;
  const float* cnt; const float* w0n;
  const int* rmap; const int* dst; const int* posN; const int* Mdev;
  float* outp; float* atomp;
  int SK, Mcap, Mfix; float gain;
};

// EPI 0: store. EPI 1: store + atomicAdd agg0c[posN[dst[rmap[m]]]].
// EPI 2: atomicAdd agg1c[dst/250]. EPI 7: +T0 +la*w0n, store. EPI 8: 14x tile to out.
template<int EPI>
__global__ __launch_bounds__(256) void epi_k(EPP e) {
  int M = e.Mdev ? *e.Mdev : e.Mfix;
  if (M > e.Mcap) M = e.Mcap;
  int i = blockIdx.x*256 + threadIdx.x;
  if (i >= M*128) return;
  int m = i >> 7, n4 = (i & 127) * 4;
  float ys[4] = {0.f, 0.f, 0.f, 0.f};
  for (int z = 0; z < e.SK; z++) {
    float4 v = *(const float4*)&e.pbuf[((size_t)z*e.Mcap + m)*512 + n4];
    ys[0] += v.x; ys[1] += v.y; ys[2] += v.z; ys[3] += v.w;
  }
  if (EPI == 7) {
    int nd = e.rmap[m];
    int rr = nd & 63;
#pragma unroll
    for (int z = 0; z < SK_T; z++) {
      float4 v = *(const float4*)&e.T0p[((size_t)z*64 + rr)*512 + n4];
      ys[0] += v.x; ys[1] += v.y; ys[2] += v.z; ys[3] += v.w;
    }
    float l0 = e.la[nd*3], l1 = e.la[nd*3+1], l2 = e.la[nd*3+2];
    bool has = e.cnt[nd] > 0.f;
#pragma unroll
    for (int j = 0; j < 4; j++) {
      int n = n4 + j;
      float corr = l0*e.w0n[0*512+n] + l1*e.w0n[1*512+n] + l2*e.w0n[2*512+n];
      if (has) corr += l0*e.w0n[3*512+n] + l1*e.w0n[4*512+n] + l2*e.w0n[5*512+n];
      ys[j] += corr;
    }
  }
#pragma unroll
  for (int j = 0; j < 4; j++) {
    float y = ys[j] * e.gain + e.bias[n4+j] * LRc;
    ys[j] = (y > 0.f ? y : 0.2f*y) * SQ2;
  }
  float4 ov = make_float4(ys[0], ys[1], ys[2], ys[3]);
  if (EPI == 0 || EPI == 7) {
    *(float4*)&e.outp[(size_t)m*512 + n4] = ov;
  } else if (EPI == 1) {
    *(float4*)&e.outp[(size_t)m*512 + n4] = ov;
    int tr = e.posN[e.dst[e.rmap[m]]];
#pragma unroll
    for (int j = 0; j < 4; j++) atomicAdd(&e.atomp[(size_t)tr*512 + n4 + j], ys[j]);
  } else if (EPI == 2) {
    int tr = e.dst[e.rmap[m]] / NVP;
#pragma unroll
    for (int j = 0; j < 4; j++) atomicAdd(&e.atomp[(size_t)tr*512 + n4 + j], ys[j]);
  } else { // 8
#pragma unroll
    for (int w = 0; w < 14; w++)
      *(float4*)&e.outp[((size_t)(m*14 + w))*512 + n4] = ov;
  }
}

// fused init: blocks 0-63 rms, 64-126 need-flags, 127-128 small-W transposes
__global__ __launch_bounds__(256) void init_k(const float* z, float* zn, int* need,
                                              const float* W0, const float* Wn,
                                              float* w0s, float* w0n) {
  int b = blockIdx.x, t = threadIdx.x;
  if (b < 64) {
    float s = 0.f;
    for (int j = t; j < 512; j += 256) { float v = z[b*512+j]; s += v*v; }
    for (int o = 32; o > 0; o >>= 1) s += __shfl_down(s, o);
    __shared__ float red[5];
    if ((t & 63) == 0) red[t >> 6] = s;
    __syncthreads();
    if (t == 0) {
      float tot = red[0]+red[1]+red[2]+red[3];
      red[4] = 1.0f / sqrtf(tot * (1.0f/512.0f) + 1e-8f);
    }
    __syncthreads();
    float r = red[4];
    for (int j = t; j < 512; j += 256) zn[b*512+j] = z[b*512+j] * r;
  } else if (b < 127) {
    int n = (b-64)*256 + t;
    if (n < NN) need[n] = ((n % NVP) == 0) ? 1 : 0;
  } else {
    int c = (b-127)*256 + t;
    const float* row = W0 + (size_t)c*1034;
    w0s[0*512+c] = row[512];  w0s[1*512+c] = row[513];  w0s[2*512+c] = row[514];
    w0s[3*512+c] = row[1027]; w0s[4*512+c] = row[1028]; w0s[5*512+c] = row[1029];
    w0s[6*512+c] = row[1030]; w0s[7*512+c] = row[1031]; w0s[8*512+c] = row[1032];
    w0s[9*512+c] = row[1033];
    const float* rn = Wn + (size_t)c*1030;
#pragma unroll
    for (int j = 0; j < 6; j++) w0n[j*512+c] = rn[512+j];
  }
}

// ---- deterministic compaction ----
__device__ __forceinline__ int blockCount(int pred, int* ws4) {
  unsigned long long m = __ballot(pred);
  int lane = threadIdx.x & 63, w = threadIdx.x >> 6;
  if (lane == 0) ws4[w] = __popcll(m);
  __syncthreads();
  return ws4[0] + ws4[1] + ws4[2] + ws4[3];
}
__device__ __forceinline__ int blockRank(int pred, int* ws4) {
  unsigned long long m = __ballot(pred);
  int lane = threadIdx.x & 63, w = threadIdx.x >> 6;
  if (lane == 0) ws4[w] = __popcll(m);
  __syncthreads();
  int off = 0;
  for (int i = 0; i < w; i++) off += ws4[i];
  return off + __popcll(m & ((1ull << lane) - 1ull));
}

__global__ __launch_bounds__(256) void cntES_k(const int* dst, float* cnt, int* bcnt) {
  __shared__ int ws4[4];
  int e = blockIdx.x*256 + threadIdx.x;
  int pred = 0;
  if (e < EN) {
    int d = dst[e];
    atomicAdd(&cnt[d], 1.0f);   // integer-valued: exact, order-free
    pred = (d % NVP) == 0;
  }
  int c = blockCount(pred, ws4);
  if (threadIdx.x == 0) bcnt[blockIdx.x] = c;
}
__global__ __launch_bounds__(256) void emitES_k(const int* src, const int* dst,
                                                const int* boff, int* listES, int* need) {
  __shared__ int ws4[4];
  int e = blockIdx.x*256 + threadIdx.x;
  int pred = (e < EN) && (dst[e] % NVP == 0);
  int rank = blockRank(pred, ws4);
  if (pred) {
    int pos = boff[blockIdx.x] + rank;
    if (pos < CAP_ES) listES[pos] = e;
    need[src[e]] = 1;
  }
}
__global__ __launch_bounds__(256) void cntE0N1_k(const int* dst, const int* need,
                                                 int* bcntE, int* bcntN) {
  __shared__ int ws4[4];
  int b = blockIdx.x;
  if (b < EBLK) {
    int e = b*256 + threadIdx.x;
    int pred = (e < EN) && need[dst[e]];
    int c = blockCount(pred, ws4);
    if (threadIdx.x == 0) bcntE[b] = c;
  } else {
    int n = (b-EBLK)*256 + threadIdx.x;
    int pred = (n < NN) && need[n];
    int c = blockCount(pred, ws4);
    if (threadIdx.x == 0) bcntN[b-EBLK] = c;
  }
}
__global__ __launch_bounds__(256) void emitE0N1_k(const int* dst, const int* need,
                                                  const int* boffE, int* listE0, int* posOf,
                                                  const int* boffN, int* listN1, int* posN) {
  __shared__ int ws4[4];
  int b = blockIdx.x;
  if (b < EBLK) {
    int e = b*256 + threadIdx.x;
    int pred = (e < EN) && need[dst[e]];
    int rank = blockRank(pred, ws4);
    if (pred) {
      int pos = boffE[b] + rank;
      if (pos < CAP_E0) { listE0[pos] = e; posOf[e] = pos; }
    }
  } else {
    int n = (b-EBLK)*256 + threadIdx.x;
    int pred = (n < NN) && need[n];
    int rank = blockRank(pred, ws4);
    if (pred) {
      int pos = boffN[b-EBLK] + rank;
      if (pos < CAP_N1) { listN1[pos] = n; posN[n] = pos; }
    }
  }
}

__global__ __launch_bounds__(512) void scan_k(const int* bcnt, int n, int* boff, int* tot) {
  __shared__ int s[512];
  int t = threadIdx.x;
  int orig = (t < n) ? bcnt[t] : 0;
  s[t] = orig;
  __syncthreads();
  for (int o = 1; o < 512; o <<= 1) {
    int v = (t >= o) ? s[t-o] : 0;
    __syncthreads();
    s[t] += v;
    __syncthreads();
  }
  if (t < n) boff[t] = s[t] - orig;
  if (t == n-1) *tot = s[t];
}
__global__ __launch_bounds__(512) void scan2_k(const int* bcntA, int nA, int* boffA, int* totA,
                                               const int* bcntB, int nB, int* boffB, int* totB) {
  const int* bcnt; int n; int* boff; int* tot;
  if (blockIdx.x == 0) { bcnt = bcntA; n = nA; boff = boffA; tot = totA; }
  else                 { bcnt = bcntB; n = nB; boff = boffB; tot = totB; }
  __shared__ int s[512];
  int t = threadIdx.x;
  int orig = (t < n) ? bcnt[t] : 0;
  s[t] = orig;
  __syncthreads();
  for (int o = 1; o < 512; o <<= 1) {
    int v = (t >= o) ? s[t-o] : 0;
    __syncthreads();
    s[t] += v;
    __syncthreads();
  }
  if (t < n) boff[t] = s[t] - orig;
  if (t == n-1) *tot = s[t];
}

// P0 edge L0 via Ts/Td partial tables, float4
__global__ __launch_bounds__(128) void edge0_k(const int* nE0p, const int* listE0,
                                               const int* src, const int* dst,
                                               const float* pbTs, const float* pbTd,
                                               const float* la, const float* w0s,
                                               const float* b0, float* h0c) {
  int i = blockIdx.x;
  int n0 = *nE0p; if (n0 > CAP_E0) n0 = CAP_E0;
  if (i >= n0) return;
  int tid = threadIdx.x;
  int e = listE0[i];
  int s = src[e], d = dst[e];
  float a0 = la[s*3], a1 = la[s*3+1], a2 = la[s*3+2];
  float c0 = la[d*3], c1 = la[d*3+1], c2 = la[d*3+2];
  float r0 = c0-a0, r1 = c1-a1, r2 = c2-a2;
  float dn = sqrtf(r0*r0 + r1*r1 + r2*r2);
  const float g = LRc / 32.1558704423f; // sqrt(1034)
  int sr = s & 63, dr = d & 63;
  int c4 = tid*4;
  float ys[4] = {0.f,0.f,0.f,0.f};
#pragma unroll
  for (int z = 0; z < SK_T; z++) {
    float4 vs = *(const float4*)&pbTs[((size_t)z*64 + sr)*512 + c4];
    float4 vd = *(const float4*)&pbTd[((size_t)z*64 + dr)*512 + c4];
    ys[0] += vs.x + vd.x; ys[1] += vs.y + vd.y;
    ys[2] += vs.z + vd.z; ys[3] += vs.w + vd.w;
  }
  float cf[10] = {a0,a1,a2,c0,c1,c2,r0,r1,r2,dn};
#pragma unroll
  for (int j = 0; j < 10; j++) {
    float4 wv = *(const float4*)&w0s[j*512 + c4];
    ys[0] += cf[j]*wv.x; ys[1] += cf[j]*wv.y; ys[2] += cf[j]*wv.z; ys[3] += cf[j]*wv.w;
  }
  float4 bv = *(const float4*)&b0[c4];
  float bb[4] = {bv.x, bv.y, bv.z, bv.w};
#pragma unroll
  for (int j = 0; j < 4; j++) {
    float y = ys[j]*g + bb[j]*LRc;
    ys[j] = (y > 0.f ? y : 0.2f*y) * SQ2;
  }
  *(float4*)&h0c[(size_t)i*512 + c4] = make_float4(ys[0],ys[1],ys[2],ys[3]);
}

__global__ __launch_bounds__(256) void buildA64_k(const int* posN, const float* x1c,
                                                  const float* agg1c, const float* cnt,
                                                  float* A64) {
  int m = blockIdx.x;
  int q = threadIdx.x;
  if (q < 128) {
    *(float4*)&A64[(size_t)m*1024 + q*4] =
      *(const float4*)&x1c[(size_t)posN[m*NVP]*512 + q*4];
  } else {
    float rinv = 1.0f / fmaxf(cnt[m*NVP], 1.0f);
    int w = (q - 128)*4;
    float4 v = *(const float4*)&agg1c[(size_t)m*512 + w];
    v.x *= rinv; v.y *= rinv; v.z *= rinv; v.w *= rinv;
    *(float4*)&A64[(size_t)m*1024 + 512 + w] = v;
  }
}

extern "C" void kernel_launch(void* const* d_in, const int* in_sizes, int n_in,
                              void* d_out, int out_size, void* d_ws, size_t ws_size,
                              hipStream_t stream) {
  const float* z     = (const float*)d_in[0];
  const float* la    = (const float*)d_in[1];
  const int*   ei    = (const int*)  d_in[2];
  const float* p0ew0 = (const float*)d_in[3];
  const float* p0eb0 = (const float*)d_in[4];
  const float* p0ew1 = (const float*)d_in[5];
  const float* p0eb1 = (const float*)d_in[6];
  const float* p0nw0 = (const float*)d_in[7];
  const float* p0nb0 = (const float*)d_in[8];
  const float* p0nw1 = (const float*)d_in[9];
  const float* p0nb1 = (const float*)d_in[10];
  const float* p1ew0 = (const float*)d_in[11];
  const float* p1eb0 = (const float*)d_in[12];
  const float* p1ew1 = (const float*)d_in[13];
  const float* p1eb1 = (const float*)d_in[14];
  const float* p1nw0 = (const float*)d_in[15];
  const float* p1nb0 = (const float*)d_in[16];
  const float* p1nw1 = (const float*)d_in[17];
  const float* p1nb1 = (const float*)d_in[18];
  const int* src = ei;
  const int* dst = ei + EN;

  char* ws = (char*)d_ws;
  size_t off = 0;
  auto al = [&](size_t bytes) -> void* {
    void* r = (void*)(ws + off);
    off += (bytes + 255) & ~(size_t)255;
    return r;
  };
  // ---- zeroed region ----
  int*   tot    = (int*)  al(3*4);
  float* cnt    = (float*)al(NN*4);
  int*   need   = (int*)  al(NN*4);
  int*   posN   = (int*)  al(NN*4);
  int*   posOf  = (int*)  al((size_t)EN*4);
  int*   bcntE  = (int*)  al(EBLK*4);
  int*   boffE  = (int*)  al(EBLK*4);
  int*   bcntN  = (int*)  al(NBLK*4);
  int*   boffN  = (int*)  al(NBLK*4);
  int*   listES = (int*)  al(CAP_ES*4);
  int*   listN1 = (int*)  al(CAP_N1*4);
  int*   listE0 = (int*)  al(CAP_E0*4);
  float* agg0c  = (float*)al((size_t)CAP_N1*512*4);
  float* agg1c  = (float*)al(64*512*4);
  size_t zEnd = off;
  // ---- written-before-read region ----
  float* zn     = (float*)al(64*512*4);
  float* w0s    = (float*)al(10*512*4);
  float* w0n    = (float*)al(6*512*4);
  float* pbTs   = (float*)al((size_t)SK_T*64*512*4);
  float* pbTd   = (float*)al((size_t)SK_T*64*512*4);
  float* pbT0   = (float*)al((size_t)SK_T*64*512*4);
  float* h0c    = (float*)al((size_t)CAP_E0*512*4);
  float* ef0c   = (float*)al((size_t)CAP_E0*512*4);
  float* hn1    = (float*)al((size_t)CAP_N1*512*4);
  float* x1c    = (float*)al((size_t)CAP_N1*512*4);
  float* hs     = (float*)al((size_t)CAP_ES*512*4);
  float* A64    = (float*)al(64*1024*4);
  float* hn64   = (float*)al(64*512*4);
  float* pbuf   = (float*)al((size_t)CAP_E0*512*2*4);   // 16.8 MB (max SK x Mcap)

  hipMemsetAsync(ws, 0, zEnd, stream);

  init_k<<<129, 256, 0, stream>>>(z, zn, need, p0ew0, p0nw0, w0s, w0n);

  cntES_k<<<EBLK, 256, 0, stream>>>(dst, cnt, bcntE);
  scan_k<<<1, 512, 0, stream>>>(bcntE, EBLK, boffE, tot+0);
  emitES_k<<<EBLK, 256, 0, stream>>>(src, dst, boffE, listES, need);

  cntE0N1_k<<<EBLK+NBLK, 256, 0, stream>>>(dst, need, bcntE, bcntN);
  scan2_k<<<2, 512, 0, stream>>>(bcntE, EBLK, boffE, tot+1, bcntN, NBLK, boffN, tot+2);
  emitE0N1_k<<<EBLK+NBLK, 256, 0, stream>>>(dst, need, boffE, listE0, posOf,
                                            boffN, listN1, posN);

  // Ts/Td/T0 tables in one launch
  {
    TABP q{zn, p0ew0, p0nw0, pbTs, pbTd, pbT0};
    tab_k<<<dim3(2, 24, SK_T), 128, 0, stream>>>(q);
  }

  edge0_k<<<CAP_E0, 128, 0, stream>>>(tot+1, listE0, src, dst, pbTs, pbTd, la, w0s,
                                      p0eb0, h0c);

  // P0 edge L1: dense K=512, SK=2 -> ef0c + atomic agg0c
  {
    GPP p{}; p.W = p0ew1; p.Wld = 512; p.Woff = 0; p.Astride = 512;
    p.K = 512; p.KC = 256; p.Mcap = CAP_E0; p.Mdev = tot+1;
    p.Ain = h0c; p.pbuf = pbuf;
    gemmP<1,0><<<dim3(CAP_E0/32, 8, 2), 128, 0, stream>>>(p);
    EPP e{}; e.pbuf = pbuf; e.SK = 2; e.Mcap = CAP_E0; e.Mdev = tot+1;
    e.bias = p0eb1; e.gain = LRc/sqrtf(512.f);
    e.rmap = listE0; e.dst = dst; e.posN = posN; e.outp = ef0c; e.atomp = agg0c;
    epi_k<1><<<(CAP_E0*128)/256, 256, 0, stream>>>(e);
  }
  // P0 node L0: row-scaled dense over raw agg0c (W cols 518..1029) + epi7
  {
    GPP p{}; p.W = p0nw0; p.Wld = 1030; p.Woff = 518; p.Astride = 512;
    p.K = 512; p.KC = 128; p.Mcap = CAP_N1; p.Mdev = tot+2;
    p.Ain = agg0c; p.cnt = cnt; p.listN1 = listN1; p.pbuf = pbuf;
    gemmP<0,1><<<dim3(CAP_N1/32, 8, 4), 128, 0, stream>>>(p);
    EPP e{}; e.pbuf = pbuf; e.SK = 4; e.Mcap = CAP_N1; e.Mdev = tot+2;
    e.bias = p0nb0; e.gain = LRc/sqrtf(1030.f);
    e.T0p = pbT0; e.rmap = listN1; e.la = la; e.cnt = cnt; e.w0n = w0n; e.outp = hn1;
    epi_k<7><<<(CAP_N1*128)/256, 256, 0, stream>>>(e);
  }
  // P0 node L1 -> x1c
  {
    GPP p{}; p.W = p0nw1; p.Wld = 512; p.Woff = 0; p.Astride = 512;
    p.K = 512; p.KC = 128; p.Mcap = CAP_N1; p.Mdev = tot+2;
    p.Ain = hn1; p.pbuf = pbuf;
    gemmP<1,0><<<dim3(CAP_N1/32, 8, 4), 128, 0, stream>>>(p);
    EPP e{}; e.pbuf = pbuf; e.SK = 4; e.Mcap = CAP_N1; e.Mdev = tot+2;
    e.bias = p0nb1; e.gain = LRc/sqrtf(512.f); e.outp = x1c;
    epi_k<0><<<(CAP_N1*128)/256, 256, 0, stream>>>(e);
  }
  // P1 edge L0: in-GEMM gather, K=1536, SK=6 -> hs
  {
    GGP p{}; p.W = p1ew0; p.x1c = x1c; p.ef0c = ef0c;
    p.listES = listES; p.src = src; p.dst = dst; p.posN = posN; p.posOf = posOf;
    p.Mdev = tot+0; p.pbuf = pbuf; p.KC = 256;
    gemmG<<<dim3(CAP_ES/32, 8, 6), 128, 0, stream>>>(p);
    EPP e{}; e.pbuf = pbuf; e.SK = 6; e.Mcap = CAP_ES; e.Mdev = tot+0;
    e.bias = p1eb0; e.gain = LRc/sqrtf(1536.f); e.outp = hs;
    epi_k<0><<<(CAP_ES*128)/256, 256, 0, stream>>>(e);
  }
  // P1 edge L1: dense K=512, SK=4 -> atomic agg1c
  {
    GPP p{}; p.W = p1ew1; p.Wld = 512; p.Woff = 0; p.Astride = 512;
    p.K = 512; p.KC = 128; p.Mcap = CAP_ES; p.Mdev = tot+0;
    p.Ain = hs; p.pbuf = pbuf;
    gemmP<1,0><<<dim3(CAP_ES/32, 8, 4), 128, 0, stream>>>(p);
    EPP e{}; e.pbuf = pbuf; e.SK = 4; e.Mcap = CAP_ES; e.Mdev = tot+0;
    e.bias = p1eb1; e.gain = LRc/sqrtf(512.f);
    e.rmap = listES; e.dst = dst; e.atomp = agg1c;
    epi_k<2><<<(CAP_ES*128)/256, 256, 0, stream>>>(e);
  }
  buildA64_k<<<64, 256, 0, stream>>>(posN, x1c, agg1c, cnt, A64);

  // P1 node L0: dense K=1024, SK=8 -> hn64
  {
    GPP p{}; p.W = p1nw0; p.Wld = 1024; p.Woff = 0; p.Astride = 1024;
    p.K = 1024; p.KC = 128; p.Mcap = 64; p.Mfix = 64; p.Mdev = nullptr;
    p.Ain = A64; p.pbuf = pbuf;
    gemmP<1,0><<<dim3(2, 8, 8), 128, 0, stream>>>(p);
    EPP e{}; e.pbuf = pbuf; e.SK = 8; e.Mcap = 64; e.Mfix = 64;
    e.bias = p1nb0; e.gain = LRc/sqrtf(1024.f); e.outp = hn64;
    epi_k<0><<<(64*128)/256, 256, 0, stream>>>(e);
  }
  // P1 node L1: dense K=512, SK=4 -> d_out (14x tiled)
  {
    GPP p{}; p.W = p1nw1; p.Wld = 512; p.Woff = 0; p.Astride = 512;
    p.K = 512; p.KC = 128; p.Mcap = 64; p.Mfix = 64; p.Mdev = nullptr;
    p.Ain = hn64; p.pbuf = pbuf;
    gemmP<1,0><<<dim3(2, 8, 4), 128, 0, stream>>>(p);
    EPP e{}; e.pbuf = pbuf; e.SK = 4; e.Mcap = 64; e.Mfix = 64;
    e.bias = p1nb1; e.gain = LRc/sqrtf(512.f); e.outp = (float*)d_out;
    epi_k<8><<<(64*128)/256, 256, 0, stream>>>(e);
  }
}

// Round 8
// 205.484 us; speedup vs baseline: 90.5575x; 1.0558x over previous
//
#include <hip/hip_runtime.h>
#include <hip/hip_bf16.h>
#include <cmath>

#define NVP 250
#define NN  16000
#define EN  95232
#define LRc 0.01f
#define SQ2 1.41421356237309515f

#define CAP_ES 1024
#define CAP_N1 1024
#define CAP_E0 4096
#define EBLK ((EN + 255) / 256)   // 372
#define NBLK ((NN + 255) / 256)   // 63
#define SK_T 4

// ---------------- pipelined GEMM inner loop ----------------
// 128 thr, BM=32, BN=64, BK=32, acc 4x4. As[kk][mr] pad36, Bs[kk][nr] pad68.
// Register-prefetch of next tile overlaps the 32-FMA compute phase.
// NSEG: 1 = single base; 2 = boundary at k=512; 3 = boundaries at 512,1024.
// Per-segment scale applied at prefetch.
template<int VECW, int NSEG>
__device__ __forceinline__ void gemm_loop(
    const float* const* b0, const float* const* b1,
    const float* sc0, const float* sc1,
    const float* w0, const float* w1, const float* w2, const float* w3,
    int kBeg, int kEnd,
    float (*As)[36], float (*Bs)[68], float acc[4][4]) {
  const int t = threadIdx.x;
  const int k4 = (t & 7) * 4;
  const int mr = t >> 3;
  const int tx = t & 15, ty = t >> 4;
  float4 ra0, ra1, rw0, rw1, rw2, rw3;
  auto lA = [&](int k0) {
    int ka = k0 + k4;
    int idx = 0;
    if (NSEG >= 2 && ka >= 512) idx = 1;
    if (NSEG == 3 && ka >= 1024) idx = 2;
    float s0 = sc0[idx], s1 = sc1[idx];
    ra0 = *(const float4*)(b0[idx] + ka);
    ra1 = *(const float4*)(b1[idx] + ka);
    ra0.x *= s0; ra0.y *= s0; ra0.z *= s0; ra0.w *= s0;
    ra1.x *= s1; ra1.y *= s1; ra1.z *= s1; ra1.w *= s1;
  };
  auto lW = [&](int k0) {
    if (VECW) {
      rw0 = *(const float4*)(w0 + k0); rw1 = *(const float4*)(w1 + k0);
      rw2 = *(const float4*)(w2 + k0); rw3 = *(const float4*)(w3 + k0);
    } else {
      rw0 = make_float4(w0[k0], w0[k0+1], w0[k0+2], w0[k0+3]);
      rw1 = make_float4(w1[k0], w1[k0+1], w1[k0+2], w1[k0+3]);
      rw2 = make_float4(w2[k0], w2[k0+1], w2[k0+2], w2[k0+3]);
      rw3 = make_float4(w3[k0], w3[k0+1], w3[k0+2], w3[k0+3]);
    }
  };
  lA(kBeg); lW(kBeg);
  for (int k0 = kBeg; k0 < kEnd; k0 += 32) {
    if (k0 > kBeg) __syncthreads();
    As[k4+0][mr] = ra0.x; As[k4+1][mr] = ra0.y;
    As[k4+2][mr] = ra0.z; As[k4+3][mr] = ra0.w;
    As[k4+0][mr+16] = ra1.x; As[k4+1][mr+16] = ra1.y;
    As[k4+2][mr+16] = ra1.z; As[k4+3][mr+16] = ra1.w;
    Bs[k4+0][mr]    = rw0.x; Bs[k4+1][mr]    = rw0.y; Bs[k4+2][mr]    = rw0.z; Bs[k4+3][mr]    = rw0.w;
    Bs[k4+0][mr+16] = rw1.x; Bs[k4+1][mr+16] = rw1.y; Bs[k4+2][mr+16] = rw1.z; Bs[k4+3][mr+16] = rw1.w;
    Bs[k4+0][mr+32] = rw2.x; Bs[k4+1][mr+32] = rw2.y; Bs[k4+2][mr+32] = rw2.z; Bs[k4+3][mr+32] = rw2.w;
    Bs[k4+0][mr+48] = rw3.x; Bs[k4+1][mr+48] = rw3.y; Bs[k4+2][mr+48] = rw3.z; Bs[k4+3][mr+48] = rw3.w;
    __syncthreads();
    if (k0 + 32 < kEnd) { lA(k0 + 32); lW(k0 + 32); }
#pragma unroll
    for (int kk = 0; kk < 32; kk++) {
      float4 a4 = *(const float4*)&As[kk][ty*4];
      float4 b4 = *(const float4*)&Bs[kk][tx*4];
      float aa[4] = {a4.x, a4.y, a4.z, a4.w};
      float bb[4] = {b4.x, b4.y, b4.z, b4.w};
#pragma unroll
      for (int i = 0; i < 4; i++)
#pragma unroll
        for (int j = 0; j < 4; j++) acc[i][j] += aa[i]*bb[j];
    }
  }
}

struct GPP {
  const float* W; const float* Ain; float* pbuf; const int* Mdev;
  const float* cnt; const int* listN1;   // SCALED only
  int Wld, Woff, Astride, K, KC, Mcap, Mfix;
};

// split-K partial writer; SCALED: A row r scaled by 1/max(cnt[listN1[r]],1)
template<int VECW, int SCALED>
__global__ __launch_bounds__(128) void gemmP(GPP p) {
  int M = p.Mdev ? *p.Mdev : p.Mfix;
  if (M > p.Mcap) M = p.Mcap;
  const int mBase = blockIdx.x * 32;
  if (mBase >= M) return;
  const int nBase = blockIdx.y * 64;
  const int z = blockIdx.z;
  int kBeg = z * p.KC;
  int kEnd = kBeg + p.KC; if (kEnd > p.K) kEnd = p.K;
  __shared__ float As[32][36];
  __shared__ float Bs[32][68];
  const int t = threadIdx.x;
  const float* b0[1]; const float* b1[1]; float sc0[1], sc1[1];
  b0[0] = p.Ain + (size_t)(mBase + (t>>3)) * p.Astride;
  b1[0] = b0[0] + (size_t)16 * p.Astride;
  sc0[0] = 1.f; sc1[0] = 1.f;
  if (SCALED) {
    sc0[0] = 1.0f / fmaxf(p.cnt[p.listN1[mBase + (t>>3)]], 1.0f);
    sc1[0] = 1.0f / fmaxf(p.cnt[p.listN1[mBase + 16 + (t>>3)]], 1.0f);
  }
  const int kofs = (t & 7)*4 + p.Woff;
  const float* w0 = p.W + (size_t)(nBase + (t>>3)) * p.Wld + kofs;
  const float* w1 = w0 + (size_t)16 * p.Wld;
  const float* w2 = w0 + (size_t)32 * p.Wld;
  const float* w3 = w0 + (size_t)48 * p.Wld;
  float acc[4][4] = {};
  gemm_loop<VECW, 1>(b0, b1, sc0, sc1, w0, w1, w2, w3, kBeg, kEnd, As, Bs, acc);
  const int tx = t & 15, ty = t >> 4;
#pragma unroll
  for (int i = 0; i < 4; i++) {
    int r = mBase + ty*4 + i;
    *(float4*)&p.pbuf[((size_t)z*p.Mcap + r)*512 + nBase + tx*4] =
      make_float4(acc[i][0],acc[i][1],acc[i][2],acc[i][3]);
  }
}

// P1 edge L0: gather A = [x1c[posN[src]] | x1c[posN[dst]] | ef0c[posOf]] in-GEMM
struct GGP {
  const float* W; const float* x1c; const float* ef0c;
  const int* listES; const int* src; const int* dst; const int* posN; const int* posOf;
  const int* Mdev; float* pbuf; int KC;
};
__global__ __launch_bounds__(128) void gemmG(GGP p) {
  int M = *p.Mdev; if (M > CAP_ES) M = CAP_ES;
  const int mBase = blockIdx.x * 32;
  if (mBase >= M) return;
  const int nBase = blockIdx.y * 64;
  const int z = blockIdx.z;
  int kBeg = z * p.KC, kEnd = kBeg + p.KC;
  __shared__ float As[32][36];
  __shared__ float Bs[32][68];
  const int t = threadIdx.x;
  int r0 = mBase + (t>>3), r1 = r0 + 16;
  int e0 = p.listES[r0], e1 = p.listES[r1];
  const float* b0[3] = {
    p.x1c  + (size_t)p.posN[p.src[e0]]*512,
    p.x1c  + (size_t)p.posN[p.dst[e0]]*512 - 512,
    p.ef0c + (size_t)p.posOf[e0]*512 - 1024 };
  const float* b1[3] = {
    p.x1c  + (size_t)p.posN[p.src[e1]]*512,
    p.x1c  + (size_t)p.posN[p.dst[e1]]*512 - 512,
    p.ef0c + (size_t)p.posOf[e1]*512 - 1024 };
  float sc0[3] = {1.f,1.f,1.f}, sc1[3] = {1.f,1.f,1.f};
  const int kofs = (t & 7)*4;
  const float* w0 = p.W + (size_t)(nBase + (t>>3)) * 1536 + kofs;
  const float* w1 = w0 + (size_t)16 * 1536;
  const float* w2 = w0 + (size_t)32 * 1536;
  const float* w3 = w0 + (size_t)48 * 1536;
  float acc[4][4] = {};
  gemm_loop<1, 3>(b0, b1, sc0, sc1, w0, w1, w2, w3, kBeg, kEnd, As, Bs, acc);
  const int tx = t & 15, ty = t >> 4;
#pragma unroll
  for (int i = 0; i < 4; i++) {
    int r = mBase + ty*4 + i;
    *(float4*)&p.pbuf[((size_t)z*CAP_ES + r)*512 + nBase + tx*4] =
      make_float4(acc[i][0],acc[i][1],acc[i][2],acc[i][3]);
  }
}

// P1 node L0 (M=64): gather A = [x1c[posN[m*250]] | agg1c[m]/cnt] in-GEMM
struct GTP {
  const float* W; const float* x1c; const float* agg1c; const float* cnt;
  const int* posN; float* pbuf; int KC;
};
__global__ __launch_bounds__(128) void gemmT(GTP p) {
  const int mBase = blockIdx.x * 32;
  const int nBase = blockIdx.y * 64;
  const int z = blockIdx.z;
  int kBeg = z * p.KC, kEnd = kBeg + p.KC;
  __shared__ float As[32][36];
  __shared__ float Bs[32][68];
  const int t = threadIdx.x;
  int r0 = mBase + (t>>3), r1 = r0 + 16;
  const float* b0[2] = { p.x1c + (size_t)p.posN[r0*NVP]*512,
                         p.agg1c + (size_t)r0*512 - 512 };
  const float* b1[2] = { p.x1c + (size_t)p.posN[r1*NVP]*512,
                         p.agg1c + (size_t)r1*512 - 512 };
  float sc0[2] = {1.f, 1.0f / fmaxf(p.cnt[r0*NVP], 1.0f)};
  float sc1[2] = {1.f, 1.0f / fmaxf(p.cnt[r1*NVP], 1.0f)};
  const int kofs = (t & 7)*4;
  const float* w0 = p.W + (size_t)(nBase + (t>>3)) * 1024 + kofs;
  const float* w1 = w0 + (size_t)16 * 1024;
  const float* w2 = w0 + (size_t)32 * 1024;
  const float* w3 = w0 + (size_t)48 * 1024;
  float acc[4][4] = {};
  gemm_loop<1, 2>(b0, b1, sc0, sc1, w0, w1, w2, w3, kBeg, kEnd, As, Bs, acc);
  const int tx = t & 15, ty = t >> 4;
#pragma unroll
  for (int i = 0; i < 4; i++) {
    int r = mBase + ty*4 + i;
    *(float4*)&p.pbuf[((size_t)z*64 + r)*512 + nBase + tx*4] =
      make_float4(acc[i][0],acc[i][1],acc[i][2],acc[i][3]);
  }
}

// fused 3-table GEMM: Ts/Td/T0, grid (2, 24, SK_T)
struct TABP { const float* zn; const float* We; const float* Wn;
              float* pbTs; float* pbTd; float* pbT0; };
__global__ __launch_bounds__(128) void tab_k(TABP q) {
  int wsel = blockIdx.y >> 3;
  int nBase = (blockIdx.y & 7) * 64;
  const float* W = (wsel == 2) ? q.Wn : q.We;
  int Wld = (wsel == 2) ? 1030 : 1034;
  int Woff = (wsel == 1) ? 515 : 0;
  float* pb = (wsel == 0) ? q.pbTs : (wsel == 1) ? q.pbTd : q.pbT0;
  int z = blockIdx.z;
  __shared__ float As[32][36];
  __shared__ float Bs[32][68];
  const int t = threadIdx.x;
  const int mBase = blockIdx.x * 32;
  const float* b0[1]; const float* b1[1]; float sc0[1] = {1.f}, sc1[1] = {1.f};
  b0[0] = q.zn + (size_t)(mBase + (t>>3)) * 512;
  b1[0] = b0[0] + 16*512;
  const int kofs = (t & 7)*4 + Woff;
  const float* w0 = W + (size_t)(nBase + (t>>3)) * Wld + kofs;
  const float* w1 = w0 + (size_t)16 * Wld;
  const float* w2 = w0 + (size_t)32 * Wld;
  const float* w3 = w0 + (size_t)48 * Wld;
  float acc[4][4] = {};
  gemm_loop<0, 1>(b0, b1, sc0, sc1, w0, w1, w2, w3, z*128, z*128+128, As, Bs, acc);
  const int tx = t & 15, ty = t >> 4;
#pragma unroll
  for (int i = 0; i < 4; i++) {
    int r = mBase + ty*4 + i;
    *(float4*)&pb[((size_t)z*64 + r)*512 + nBase + tx*4] =
      make_float4(acc[i][0],acc[i][1],acc[i][2],acc[i][3]);
  }
}

struct EPP {
  const float* pbuf; const float* bias; const float* T0p; const float* la;
  const float* cnt; const float* w0n;
  const int* rmap; const int* dst; const int* posN; const int* Mdev;
  float* outp; float* atomp;
  int SK, Mcap, Mfix; float gain;
};

// EPI 0: store. EPI 1: store + atomicAdd agg0c[posN[dst[rmap[m]]]].
// EPI 2: atomicAdd agg1c[dst/250]. EPI 7: +T0 +la*w0n, store. EPI 8: 14x tile to out.
template<int EPI>
__global__ __launch_bounds__(256) void epi_k(EPP e) {
  int M = e.Mdev ? *e.Mdev : e.Mfix;
  if (M > e.Mcap) M = e.Mcap;
  int i = blockIdx.x*256 + threadIdx.x;
  if (i >= M*128) return;
  int m = i >> 7, n4 = (i & 127) * 4;
  float ys[4] = {0.f, 0.f, 0.f, 0.f};
  for (int z = 0; z < e.SK; z++) {
    float4 v = *(const float4*)&e.pbuf[((size_t)z*e.Mcap + m)*512 + n4];
    ys[0] += v.x; ys[1] += v.y; ys[2] += v.z; ys[3] += v.w;
  }
  if (EPI == 7) {
    int nd = e.rmap[m];
    int rr = nd & 63;
#pragma unroll
    for (int z = 0; z < SK_T; z++) {
      float4 v = *(const float4*)&e.T0p[((size_t)z*64 + rr)*512 + n4];
      ys[0] += v.x; ys[1] += v.y; ys[2] += v.z; ys[3] += v.w;
    }
    float l0 = e.la[nd*3], l1 = e.la[nd*3+1], l2 = e.la[nd*3+2];
    bool has = e.cnt[nd] > 0.f;
#pragma unroll
    for (int j = 0; j < 4; j++) {
      int n = n4 + j;
      float corr = l0*e.w0n[0*512+n] + l1*e.w0n[1*512+n] + l2*e.w0n[2*512+n];
      if (has) corr += l0*e.w0n[3*512+n] + l1*e.w0n[4*512+n] + l2*e.w0n[5*512+n];
      ys[j] += corr;
    }
  }
#pragma unroll
  for (int j = 0; j < 4; j++) {
    float y = ys[j] * e.gain + e.bias[n4+j] * LRc;
    ys[j] = (y > 0.f ? y : 0.2f*y) * SQ2;
  }
  float4 ov = make_float4(ys[0], ys[1], ys[2], ys[3]);
  if (EPI == 0 || EPI == 7) {
    *(float4*)&e.outp[(size_t)m*512 + n4] = ov;
  } else if (EPI == 1) {
    *(float4*)&e.outp[(size_t)m*512 + n4] = ov;
    int tr = e.posN[e.dst[e.rmap[m]]];
#pragma unroll
    for (int j = 0; j < 4; j++) atomicAdd(&e.atomp[(size_t)tr*512 + n4 + j], ys[j]);
  } else if (EPI == 2) {
    int tr = e.dst[e.rmap[m]] / NVP;
#pragma unroll
    for (int j = 0; j < 4; j++) atomicAdd(&e.atomp[(size_t)tr*512 + n4 + j], ys[j]);
  } else { // 8
#pragma unroll
    for (int w = 0; w < 14; w++)
      *(float4*)&e.outp[((size_t)(m*14 + w))*512 + n4] = ov;
  }
}

// fused init: blocks 0-63 rms, 64-126 need-flags, 127-128 small-W transposes
__global__ __launch_bounds__(256) void init_k(const float* z, float* zn, int* need,
                                              const float* W0, const float* Wn,
                                              float* w0s, float* w0n) {
  int b = blockIdx.x, t = threadIdx.x;
  if (b < 64) {
    float s = 0.f;
    for (int j = t; j < 512; j += 256) { float v = z[b*512+j]; s += v*v; }
    for (int o = 32; o > 0; o >>= 1) s += __shfl_down(s, o);
    __shared__ float red[5];
    if ((t & 63) == 0) red[t >> 6] = s;
    __syncthreads();
    if (t == 0) {
      float tot = red[0]+red[1]+red[2]+red[3];
      red[4] = 1.0f / sqrtf(tot * (1.0f/512.0f) + 1e-8f);
    }
    __syncthreads();
    float r = red[4];
    for (int j = t; j < 512; j += 256) zn[b*512+j] = z[b*512+j] * r;
  } else if (b < 127) {
    int n = (b-64)*256 + t;
    if (n < NN) need[n] = ((n % NVP) == 0) ? 1 : 0;
  } else {
    int c = (b-127)*256 + t;
    const float* row = W0 + (size_t)c*1034;
    w0s[0*512+c] = row[512];  w0s[1*512+c] = row[513];  w0s[2*512+c] = row[514];
    w0s[3*512+c] = row[1027]; w0s[4*512+c] = row[1028]; w0s[5*512+c] = row[1029];
    w0s[6*512+c] = row[1030]; w0s[7*512+c] = row[1031]; w0s[8*512+c] = row[1032];
    w0s[9*512+c] = row[1033];
    const float* rn = Wn + (size_t)c*1030;
#pragma unroll
    for (int j = 0; j < 6; j++) w0n[j*512+c] = rn[512+j];
  }
}

// ---- deterministic compaction ----
__device__ __forceinline__ int blockCount(int pred, int* ws4) {
  unsigned long long m = __ballot(pred);
  int lane = threadIdx.x & 63, w = threadIdx.x >> 6;
  if (lane == 0) ws4[w] = __popcll(m);
  __syncthreads();
  return ws4[0] + ws4[1] + ws4[2] + ws4[3];
}
__device__ __forceinline__ int blockRank(int pred, int* ws4) {
  unsigned long long m = __ballot(pred);
  int lane = threadIdx.x & 63, w = threadIdx.x >> 6;
  if (lane == 0) ws4[w] = __popcll(m);
  __syncthreads();
  int off = 0;
  for (int i = 0; i < w; i++) off += ws4[i];
  return off + __popcll(m & ((1ull << lane) - 1ull));
}

// count ES + cnt atomic + mark need[src] (plain store of 1: order-free)
__global__ __launch_bounds__(256) void cntES_k(const int* src, const int* dst,
                                               float* cnt, int* need, int* bcnt) {
  __shared__ int ws4[4];
  int e = blockIdx.x*256 + threadIdx.x;
  int pred = 0;
  if (e < EN) {
    int d = dst[e];
    atomicAdd(&cnt[d], 1.0f);   // integer-valued: exact, order-free
    pred = (d % NVP) == 0;
    if (pred) need[src[e]] = 1;
  }
  int c = blockCount(pred, ws4);
  if (threadIdx.x == 0) bcnt[blockIdx.x] = c;
}
__global__ __launch_bounds__(256) void cntE0N1_k(const int* dst, const int* need,
                                                 int* bcntE, int* bcntN) {
  __shared__ int ws4[4];
  int b = blockIdx.x;
  if (b < EBLK) {
    int e = b*256 + threadIdx.x;
    int pred = (e < EN) && need[dst[e]];
    int c = blockCount(pred, ws4);
    if (threadIdx.x == 0) bcntE[b] = c;
  } else {
    int n = (b-EBLK)*256 + threadIdx.x;
    int pred = (n < NN) && need[n];
    int c = blockCount(pred, ws4);
    if (threadIdx.x == 0) bcntN[b-EBLK] = c;
  }
}
// 3 scans in one launch
__global__ __launch_bounds__(512) void scan3_k(const int* bA, int nA, int* oA, int* tA,
                                               const int* bB, int nB, int* oB, int* tB,
                                               const int* bC, int nC, int* oC, int* tC) {
  const int* bcnt; int n; int* boff; int* tot;
  if (blockIdx.x == 0)      { bcnt = bA; n = nA; boff = oA; tot = tA; }
  else if (blockIdx.x == 1) { bcnt = bB; n = nB; boff = oB; tot = tB; }
  else                      { bcnt = bC; n = nC; boff = oC; tot = tC; }
  __shared__ int s[512];
  int t = threadIdx.x;
  int orig = (t < n) ? bcnt[t] : 0;
  s[t] = orig;
  __syncthreads();
  for (int o = 1; o < 512; o <<= 1) {
    int v = (t >= o) ? s[t-o] : 0;
    __syncthreads();
    s[t] += v;
    __syncthreads();
  }
  if (t < n) boff[t] = s[t] - orig;
  if (t == n-1) *tot = s[t];
}
// fused emit: blocks [0,EBLK) ES, [EBLK,2*EBLK) E0, rest N1
__global__ __launch_bounds__(256) void emit3_k(const int* src, const int* dst,
                                               const int* need,
                                               const int* boffS, int* listES,
                                               const int* boffE, int* listE0, int* posOf,
                                               const int* boffN, int* listN1, int* posN) {
  __shared__ int ws4[4];
  int b = blockIdx.x;
  if (b < EBLK) {
    int e = b*256 + threadIdx.x;
    int pred = (e < EN) && (dst[e] % NVP == 0);
    int rank = blockRank(pred, ws4);
    if (pred) {
      int pos = boffS[b] + rank;
      if (pos < CAP_ES) listES[pos] = e;
    }
  } else if (b < 2*EBLK) {
    int e = (b-EBLK)*256 + threadIdx.x;
    int pred = (e < EN) && need[dst[e]];
    int rank = blockRank(pred, ws4);
    if (pred) {
      int pos = boffE[b-EBLK] + rank;
      if (pos < CAP_E0) { listE0[pos] = e; posOf[e] = pos; }
    }
  } else {
    int n = (b-2*EBLK)*256 + threadIdx.x;
    int pred = (n < NN) && need[n];
    int rank = blockRank(pred, ws4);
    if (pred) {
      int pos = boffN[b-2*EBLK] + rank;
      if (pos < CAP_N1) { listN1[pos] = n; posN[n] = pos; }
    }
  }
}

// P0 edge L0 via Ts/Td partial tables, float4
__global__ __launch_bounds__(128) void edge0_k(const int* nE0p, const int* listE0,
                                               const int* src, const int* dst,
                                               const float* pbTs, const float* pbTd,
                                               const float* la, const float* w0s,
                                               const float* b0, float* h0c) {
  int i = blockIdx.x;
  int n0 = *nE0p; if (n0 > CAP_E0) n0 = CAP_E0;
  if (i >= n0) return;
  int tid = threadIdx.x;
  int e = listE0[i];
  int s = src[e], d = dst[e];
  float a0 = la[s*3], a1 = la[s*3+1], a2 = la[s*3+2];
  float c0 = la[d*3], c1 = la[d*3+1], c2 = la[d*3+2];
  float r0 = c0-a0, r1 = c1-a1, r2 = c2-a2;
  float dn = sqrtf(r0*r0 + r1*r1 + r2*r2);
  const float g = LRc / 32.1558704423f; // sqrt(1034)
  int sr = s & 63, dr = d & 63;
  int c4 = tid*4;
  float ys[4] = {0.f,0.f,0.f,0.f};
#pragma unroll
  for (int z = 0; z < SK_T; z++) {
    float4 vs = *(const float4*)&pbTs[((size_t)z*64 + sr)*512 + c4];
    float4 vd = *(const float4*)&pbTd[((size_t)z*64 + dr)*512 + c4];
    ys[0] += vs.x + vd.x; ys[1] += vs.y + vd.y;
    ys[2] += vs.z + vd.z; ys[3] += vs.w + vd.w;
  }
  float cf[10] = {a0,a1,a2,c0,c1,c2,r0,r1,r2,dn};
#pragma unroll
  for (int j = 0; j < 10; j++) {
    float4 wv = *(const float4*)&w0s[j*512 + c4];
    ys[0] += cf[j]*wv.x; ys[1] += cf[j]*wv.y; ys[2] += cf[j]*wv.z; ys[3] += cf[j]*wv.w;
  }
  float4 bv = *(const float4*)&b0[c4];
  float bb[4] = {bv.x, bv.y, bv.z, bv.w};
#pragma unroll
  for (int j = 0; j < 4; j++) {
    float y = ys[j]*g + bb[j]*LRc;
    ys[j] = (y > 0.f ? y : 0.2f*y) * SQ2;
  }
  *(float4*)&h0c[(size_t)i*512 + c4] = make_float4(ys[0],ys[1],ys[2],ys[3]);
}

extern "C" void kernel_launch(void* const* d_in, const int* in_sizes, int n_in,
                              void* d_out, int out_size, void* d_ws, size_t ws_size,
                              hipStream_t stream) {
  const float* z     = (const float*)d_in[0];
  const float* la    = (const float*)d_in[1];
  const int*   ei    = (const int*)  d_in[2];
  const float* p0ew0 = (const float*)d_in[3];
  const float* p0eb0 = (const float*)d_in[4];
  const float* p0ew1 = (const float*)d_in[5];
  const float* p0eb1 = (const float*)d_in[6];
  const float* p0nw0 = (const float*)d_in[7];
  const float* p0nb0 = (const float*)d_in[8];
  const float* p0nw1 = (const float*)d_in[9];
  const float* p0nb1 = (const float*)d_in[10];
  const float* p1ew0 = (const float*)d_in[11];
  const float* p1eb0 = (const float*)d_in[12];
  const float* p1ew1 = (const float*)d_in[13];
  const float* p1eb1 = (const float*)d_in[14];
  const float* p1nw0 = (const float*)d_in[15];
  const float* p1nb0 = (const float*)d_in[16];
  const float* p1nw1 = (const float*)d_in[17];
  const float* p1nb1 = (const float*)d_in[18];
  const int* src = ei;
  const int* dst = ei + EN;

  char* ws = (char*)d_ws;
  size_t off = 0;
  auto al = [&](size_t bytes) -> void* {
    void* r = (void*)(ws + off);
    off += (bytes + 255) & ~(size_t)255;
    return r;
  };
  // ---- zeroed region ----
  int*   tot    = (int*)  al(3*4);
  float* cnt    = (float*)al(NN*4);
  int*   need   = (int*)  al(NN*4);
  int*   posN   = (int*)  al(NN*4);
  int*   posOf  = (int*)  al((size_t)EN*4);
  int*   bcntS  = (int*)  al(EBLK*4);
  int*   boffS  = (int*)  al(EBLK*4);
  int*   bcntE  = (int*)  al(EBLK*4);
  int*   boffE  = (int*)  al(EBLK*4);
  int*   bcntN  = (int*)  al(NBLK*4);
  int*   boffN  = (int*)  al(NBLK*4);
  int*   listES = (int*)  al(CAP_ES*4);
  int*   listN1 = (int*)  al(CAP_N1*4);
  int*   listE0 = (int*)  al(CAP_E0*4);
  float* agg0c  = (float*)al((size_t)CAP_N1*512*4);
  float* agg1c  = (float*)al(64*512*4);
  size_t zEnd = off;
  // ---- written-before-read region ----
  float* zn     = (float*)al(64*512*4);
  float* w0s    = (float*)al(10*512*4);
  float* w0n    = (float*)al(6*512*4);
  float* pbTs   = (float*)al((size_t)SK_T*64*512*4);
  float* pbTd   = (float*)al((size_t)SK_T*64*512*4);
  float* pbT0   = (float*)al((size_t)SK_T*64*512*4);
  float* h0c    = (float*)al((size_t)CAP_E0*512*4);
  float* ef0c   = (float*)al((size_t)CAP_E0*512*4);
  float* hn1    = (float*)al((size_t)CAP_N1*512*4);
  float* x1c    = (float*)al((size_t)CAP_N1*512*4);
  float* hs     = (float*)al((size_t)CAP_ES*512*4);
  float* hn64   = (float*)al(64*512*4);
  float* pbuf   = (float*)al((size_t)16384*512*4);   // 33.5 MB: max SK x Mcap rows

  hipMemsetAsync(ws, 0, zEnd, stream);

  init_k<<<129, 256, 0, stream>>>(z, zn, need, p0ew0, p0nw0, w0s, w0n);

  cntES_k<<<EBLK, 256, 0, stream>>>(src, dst, cnt, need, bcntS);
  cntE0N1_k<<<EBLK+NBLK, 256, 0, stream>>>(dst, need, bcntE, bcntN);
  scan3_k<<<3, 512, 0, stream>>>(bcntS, EBLK, boffS, tot+0,
                                 bcntE, EBLK, boffE, tot+1,
                                 bcntN, NBLK, boffN, tot+2);
  emit3_k<<<2*EBLK+NBLK, 256, 0, stream>>>(src, dst, need, boffS, listES,
                                           boffE, listE0, posOf, boffN, listN1, posN);

  // Ts/Td/T0 tables in one launch
  {
    TABP q{zn, p0ew0, p0nw0, pbTs, pbTd, pbT0};
    tab_k<<<dim3(2, 24, SK_T), 128, 0, stream>>>(q);
  }

  edge0_k<<<CAP_E0, 128, 0, stream>>>(tot+1, listE0, src, dst, pbTs, pbTd, la, w0s,
                                      p0eb0, h0c);

  // P0 edge L1: dense K=512, SK=4 -> ef0c + atomic agg0c
  {
    GPP p{}; p.W = p0ew1; p.Wld = 512; p.Woff = 0; p.Astride = 512;
    p.K = 512; p.KC = 128; p.Mcap = CAP_E0; p.Mdev = tot+1;
    p.Ain = h0c; p.pbuf = pbuf;
    gemmP<1,0><<<dim3(CAP_E0/32, 8, 4), 128, 0, stream>>>(p);
    EPP e{}; e.pbuf = pbuf; e.SK = 4; e.Mcap = CAP_E0; e.Mdev = tot+1;
    e.bias = p0eb1; e.gain = LRc/sqrtf(512.f);
    e.rmap = listE0; e.dst = dst; e.posN = posN; e.outp = ef0c; e.atomp = agg0c;
    epi_k<1><<<(CAP_E0*128)/256, 256, 0, stream>>>(e);
  }
  // P0 node L0: row-scaled dense over raw agg0c (W cols 518..1029) + epi7
  {
    GPP p{}; p.W = p0nw0; p.Wld = 1030; p.Woff = 518; p.Astride = 512;
    p.K = 512; p.KC = 64; p.Mcap = CAP_N1; p.Mdev = tot+2;
    p.Ain = agg0c; p.cnt = cnt; p.listN1 = listN1; p.pbuf = pbuf;
    gemmP<0,1><<<dim3(CAP_N1/32, 8, 8), 128, 0, stream>>>(p);
    EPP e{}; e.pbuf = pbuf; e.SK = 8; e.Mcap = CAP_N1; e.Mdev = tot+2;
    e.bias = p0nb0; e.gain = LRc/sqrtf(1030.f);
    e.T0p = pbT0; e.rmap = listN1; e.la = la; e.cnt = cnt; e.w0n = w0n; e.outp = hn1;
    epi_k<7><<<(CAP_N1*128)/256, 256, 0, stream>>>(e);
  }
  // P0 node L1 -> x1c
  {
    GPP p{}; p.W = p0nw1; p.Wld = 512; p.Woff = 0; p.Astride = 512;
    p.K = 512; p.KC = 64; p.Mcap = CAP_N1; p.Mdev = tot+2;
    p.Ain = hn1; p.pbuf = pbuf;
    gemmP<1,0><<<dim3(CAP_N1/32, 8, 8), 128, 0, stream>>>(p);
    EPP e{}; e.pbuf = pbuf; e.SK = 8; e.Mcap = CAP_N1; e.Mdev = tot+2;
    e.bias = p0nb1; e.gain = LRc/sqrtf(512.f); e.outp = x1c;
    epi_k<0><<<(CAP_N1*128)/256, 256, 0, stream>>>(e);
  }
  // P1 edge L0: in-GEMM gather, K=1536, SK=12 -> hs
  {
    GGP p{}; p.W = p1ew0; p.x1c = x1c; p.ef0c = ef0c;
    p.listES = listES; p.src = src; p.dst = dst; p.posN = posN; p.posOf = posOf;
    p.Mdev = tot+0; p.pbuf = pbuf; p.KC = 128;
    gemmG<<<dim3(CAP_ES/32, 8, 12), 128, 0, stream>>>(p);
    EPP e{}; e.pbuf = pbuf; e.SK = 12; e.Mcap = CAP_ES; e.Mdev = tot+0;
    e.bias = p1eb0; e.gain = LRc/sqrtf(1536.f); e.outp = hs;
    epi_k<0><<<(CAP_ES*128)/256, 256, 0, stream>>>(e);
  }
  // P1 edge L1: dense K=512, SK=4 -> atomic agg1c
  {
    GPP p{}; p.W = p1ew1; p.Wld = 512; p.Woff = 0; p.Astride = 512;
    p.K = 512; p.KC = 128; p.Mcap = CAP_ES; p.Mdev = tot+0;
    p.Ain = hs; p.pbuf = pbuf;
    gemmP<1,0><<<dim3(CAP_ES/32, 8, 4), 128, 0, stream>>>(p);
    EPP e{}; e.pbuf = pbuf; e.SK = 4; e.Mcap = CAP_ES; e.Mdev = tot+0;
    e.bias = p1eb1; e.gain = LRc/sqrtf(512.f);
    e.rmap = listES; e.dst = dst; e.atomp = agg1c;
    epi_k<2><<<(CAP_ES*128)/256, 256, 0, stream>>>(e);
  }
  // P1 node L0: in-GEMM gather [x1c | agg1c/cnt], K=1024, SK=8 -> hn64
  {
    GTP p{}; p.W = p1nw0; p.x1c = x1c; p.agg1c = agg1c; p.cnt = cnt;
    p.posN = posN; p.pbuf = pbuf; p.KC = 128;
    gemmT<<<dim3(2, 8, 8), 128, 0, stream>>>(p);
    EPP e{}; e.pbuf = pbuf; e.SK = 8; e.Mcap = 64; e.Mfix = 64;
    e.bias = p1nb0; e.gain = LRc/sqrtf(1024.f); e.outp = hn64;
    epi_k<0><<<(64*128)/256, 256, 0, stream>>>(e);
  }
  // P1 node L1: dense K=512, SK=4 -> d_out (14x tiled)
  {
    GPP p{}; p.W = p1nw1; p.Wld = 512; p.Woff = 0; p.Astride = 512;
    p.K = 512; p.KC = 128; p.Mcap = 64; p.Mfix = 64; p.Mdev = nullptr;
    p.Ain = hn64; p.pbuf = pbuf;
    gemmP<1,0><<<dim3(2, 8, 4), 128, 0, stream>>>(p);
    EPP e{}; e.pbuf = pbuf; e.SK = 4; e.Mcap = 64; e.Mfix = 64;
    e.bias = p1nb1; e.gain = LRc/sqrtf(512.f); e.outp = (float*)d_out;
    epi_k<8><<<(64*128)/256, 256, 0, stream>>>(e);
  }
}